// Round 2
// baseline (666.331 us; speedup 1.0000x reference)
//
#include <hip/hip_runtime.h>

typedef short bf8 __attribute__((ext_vector_type(8)));      // 8 bf16 bit-patterns (4 VGPR) - MFMA A/B frag
typedef float f32x4 __attribute__((ext_vector_type(4)));    // MFMA C/D frag
typedef unsigned short us4 __attribute__((ext_vector_type(4)));
typedef unsigned short us8 __attribute__((ext_vector_type(8)));

#define DEVI __device__ __forceinline__

constexpr int NB = 8, NC = 512, NIC = 256, NS = 4096;   // batch, C, IC, N=H*W

// workspace layout (bytes)
constexpr size_t OFF_XT  = 0;          // xT   [8][4096][512] bf16 (x transposed, n-major)
constexpr size_t OFF_TP  = 33554432;   // tp   [8][4096][512] bf16 (cols 0-255 phiT, 256-511 thetaT)
constexpr size_t OFF_POS = 67108864;   // posb [4096][4096] bf16
constexpr size_t OFF_G   = 100663296;  // gb   [8][256][4096] bf16  (g + pos_dec, unscaled)
constexpr size_t OFF_RS  = 117440512;  // rs   [8][4096] f32  (1/s_j)
constexpr size_t OFF_Y   = 134217728;  // yb   [8][4096][256] bf16
constexpr size_t OFF_WTP = 150994944;  // wtp  [512][512] bf16 (rows 0-255 w_phi, 256-511 w_theta)
constexpr size_t OFF_WG  = 151519232;  // wgb  [256][512] bf16
constexpr size_t OFF_WM  = 151781376;  // wmb  [512][256] bf16
constexpr size_t OFF_SP  = 152043520;  // sp   [8][4][4096] f32 partial column sum-exp

DEVI unsigned short f2bf(float f){
  unsigned u = __float_as_uint(f);
  u += 0x7fffu + ((u >> 16) & 1u);   // RNE
  return (unsigned short)(u >> 16);
}
DEVI float bf2f(unsigned short b){ return __uint_as_float(((unsigned)b) << 16); }

DEVI void gld16(const void* g, void* l){
  __builtin_amdgcn_global_load_lds((const __attribute__((address_space(1))) unsigned int*)g,
                                   (__attribute__((address_space(3))) unsigned int*)l, 16, 0, 0);
}

// stage a [128 rows x 32 cols] bf16 tile, linear LDS, 4 waves (256 threads)
DEVI void stage128x32(unsigned short* dst, const unsigned short* src, int ld, int wid, int lane){
#pragma unroll
  for (int r = 0; r < 2; ++r){
    int instr = wid + r * 4;                 // 8 x 1024B
    int row = instr * 16 + (lane >> 2);
    gld16(src + (size_t)row * ld + (lane & 3) * 8, dst + instr * 512);
  }
}

// stage a [128 rows x 32 cols] bf16 tile, linear LDS, 8 waves (512 threads): 1 gld16/thread
DEVI void stageA8(unsigned short* dst, const unsigned short* src, int ld, int wid, int lane){
  int row = wid * 16 + (lane >> 2);
  gld16(src + (size_t)row * ld + (lane & 3) * 8, dst + wid * 512);
}

DEVI void zero44(f32x4 (&a)[4][4]){
  f32x4 z = {0.f, 0.f, 0.f, 0.f};
#pragma unroll
  for (int i = 0; i < 4; ++i)
#pragma unroll
    for (int j = 0; j < 4; ++j) a[i][j] = z;
}

// 128x128 tile GEMM, K = NK*32.  A rows = m (stride lda), B rows = n (stride ldb).
// D frag (fr,fc): m = wr*64+fr*16+(lane>>4)*4+reg, n = wc*64+fc*16+(lane&15)
template<int NK>
DEVI void gemm128(const unsigned short* Ag, int lda, const unsigned short* Bg, int ldb,
                  unsigned short (&Ab)[2][4096], unsigned short (&Bb)[2][4096],
                  f32x4 (&acc)[4][4], int wid, int lane)
{
  const int wr = wid >> 1, wc = wid & 1;
  stage128x32(Ab[0], Ag, lda, wid, lane);
  stage128x32(Bb[0], Bg, ldb, wid, lane);
  __syncthreads();
  for (int kk = 0; kk < NK; ++kk){
    int cur = kk & 1;
    if (kk + 1 < NK){
      stage128x32(Ab[cur ^ 1], Ag + (kk + 1) * 32, lda, wid, lane);
      stage128x32(Bb[cur ^ 1], Bg + (kk + 1) * 32, ldb, wid, lane);
    }
    bf8 a[4], b[4];
#pragma unroll
    for (int f = 0; f < 4; ++f){
      a[f] = *(const bf8*)&Ab[cur][(wr * 64 + f * 16 + (lane & 15)) * 32 + (lane >> 4) * 8];
      b[f] = *(const bf8*)&Bb[cur][(wc * 64 + f * 16 + (lane & 15)) * 32 + (lane >> 4) * 8];
    }
#pragma unroll
    for (int i = 0; i < 4; ++i)
#pragma unroll
      for (int j = 0; j < 4; ++j)
        acc[i][j] = __builtin_amdgcn_mfma_f32_16x16x32_bf16(a[i], b[j], acc[i][j], 0, 0, 0);
    __syncthreads();
  }
}

// ---------------- small prep kernels ----------------

__global__ void k_prep(const float* wphi, const float* wtheta, const float* wgf, const float* wmf,
                       unsigned short* wtp, unsigned short* wgb, unsigned short* wmb){
  int idx = (blockIdx.x * 256 + threadIdx.x) * 4;
  const float* src; unsigned short* dst;
  if (idx < 131072)      { src = wphi + idx;            dst = wtp + idx; }
  else if (idx < 262144) { src = wtheta + (idx - 131072); dst = wtp + idx; }
  else if (idx < 393216) { src = wgf + (idx - 262144);  dst = wgb + (idx - 262144); }
  else                   { src = wmf + (idx - 393216);  dst = wmb + (idx - 393216); }
  f32x4 v = *(const f32x4*)src;
  us4 o;
#pragma unroll
  for (int r = 0; r < 4; ++r) o[r] = f2bf(v[r]);
  *(us4*)dst = o;
}

__global__ void k_pos(const float* pos, unsigned short* posb){
  size_t base = ((size_t)blockIdx.x * 256 + threadIdx.x) * 8;
  f32x4 v0 = *(const f32x4*)&pos[base];
  f32x4 v1 = *(const f32x4*)&pos[base + 4];
  us8 o;
#pragma unroll
  for (int r = 0; r < 4; ++r){ o[r] = f2bf(v0[r]); o[r + 4] = f2bf(v1[r]); }
  *(us8*)&posb[base] = o;
}

// x [b][512][4096] f32 -> xT [b][4096][512] bf16
__global__ void k_xt(const float* x, unsigned short* xT){
  int b = blockIdx.z, ct = blockIdx.y, nt = blockIdx.x;
  __shared__ float t[64][65];
  int tid = threadIdx.x;
  int c0 = ct * 64, n0 = nt * 64;
  const float* xp = x + (size_t)b * NC * NS;
#pragma unroll
  for (int it = 0; it < 16; ++it){
    int idx = it * 256 + tid; int r = idx >> 6, cc = idx & 63;
    t[r][cc] = xp[(size_t)(c0 + r) * NS + n0 + cc];
  }
  __syncthreads();
  unsigned short* xo = xT + (size_t)b * NS * NC;
#pragma unroll
  for (int it = 0; it < 16; ++it){
    int idx = it * 256 + tid; int r = idx >> 6, cc = idx & 63;
    xo[(size_t)(n0 + r) * NC + c0 + cc] = f2bf(t[cc][r]);
  }
}

// ---------------- projection GEMMs ----------------

// tp[b][n][o] = sum_c wtp[o][c] * xT[b][n][c]   (A = wtp rows o, B = xT rows n)
__global__ __launch_bounds__(256, 2) void k_tp(const unsigned short* wtp, const unsigned short* xT,
                                               unsigned short* tp){
  int b = blockIdx.z, ot = blockIdx.y, nt = blockIdx.x;
  int tid = threadIdx.x, wid = tid >> 6, lane = tid & 63, wr = wid >> 1, wc = wid & 1;
  __shared__ unsigned short Ab[2][4096], Bb[2][4096];
  f32x4 acc[4][4]; zero44(acc);
  gemm128<16>(wtp + (size_t)(ot * 128) * 512, 512,
              xT + ((size_t)b * NS + nt * 128) * 512, 512, Ab, Bb, acc, wid, lane);
  unsigned short* out = tp + (size_t)b * NS * 512;
#pragma unroll
  for (int fr = 0; fr < 4; ++fr)
#pragma unroll
    for (int fc = 0; fc < 4; ++fc){
      int o0 = ot * 128 + wr * 64 + fr * 16 + ((lane >> 4) << 2);
      int n  = nt * 128 + wc * 64 + fc * 16 + (lane & 15);
      us4 v;
#pragma unroll
      for (int r = 0; r < 4; ++r) v[r] = f2bf(acc[fr][fc][r]);
      *(us4*)&out[(size_t)n * 512 + o0] = v;
    }
}

// gb[b][o][n] = sum_c xT[b][n][c]*wgb[o][c] + pdec[o][n]   (A = xT rows n, B = wgb rows o)
__global__ __launch_bounds__(256, 2) void k_g(const unsigned short* xT, const unsigned short* wgb,
                                              const float* pdec, unsigned short* gb){
  int b = blockIdx.z, ot = blockIdx.y, nt = blockIdx.x;
  int tid = threadIdx.x, wid = tid >> 6, lane = tid & 63, wr = wid >> 1, wc = wid & 1;
  __shared__ unsigned short Ab[2][4096], Bb[2][4096];
  f32x4 acc[4][4]; zero44(acc);
  gemm128<16>(xT + ((size_t)b * NS + nt * 128) * 512, 512,
              wgb + (size_t)(ot * 128) * 512, 512, Ab, Bb, acc, wid, lane);
#pragma unroll
  for (int fr = 0; fr < 4; ++fr)
#pragma unroll
    for (int fc = 0; fc < 4; ++fc){
      int n0 = nt * 128 + wr * 64 + fr * 16 + ((lane >> 4) << 2);
      int o  = ot * 128 + wc * 64 + fc * 16 + (lane & 15);
      f32x4 pd = *(const f32x4*)&pdec[(size_t)o * NS + n0];
      us4 v;
#pragma unroll
      for (int r = 0; r < 4; ++r) v[r] = f2bf(acc[fr][fc][r] + pd[r]);
      *(us4*)&gb[((size_t)b * NIC + o) * NS + n0] = v;
    }
}

// ---------------- softmax denominators ----------------
// Lt[j][i] = sum_c phiT[j][c]*thetaT[i][c]; sp[b][ih][j] = sum_{i in chunk} exp(Lt + pos[i][j])
__global__ __launch_bounds__(256, 2) void k_stats(const unsigned short* tp, const unsigned short* posb,
                                                  float* sp){
  int b = blockIdx.z, ih = blockIdx.y, jt = blockIdx.x;
  int tid = threadIdx.x, wid = tid >> 6, lane = tid & 63, wr = wid >> 1, wc = wid & 1;
  __shared__ unsigned short Ab[2][4096], Bb[2][4096];
  __shared__ float sred[2][2][64];
  float sacc[4][4];   // [fr][r] -> local j
#pragma unroll
  for (int i = 0; i < 4; ++i)
#pragma unroll
    for (int j = 0; j < 4; ++j) sacc[i][j] = 0.f;
  const unsigned short* tpb = tp + (size_t)b * NS * 512;
  const unsigned short* Ag = tpb + (size_t)(jt * 128) * 512;         // phiT rows j
  for (int it8 = 0; it8 < 8; ++it8){
    int i0 = (ih * 8 + it8) * 128;
    const unsigned short* Bg = tpb + (size_t)i0 * 512 + 256;         // thetaT rows i
    f32x4 acc[4][4]; zero44(acc);
    gemm128<8>(Ag, 512, Bg, 512, Ab, Bb, acc, wid, lane);
#pragma unroll
    for (int fr = 0; fr < 4; ++fr)
#pragma unroll
      for (int fc = 0; fc < 4; ++fc){
        int ig  = i0 + wc * 64 + fc * 16 + (lane & 15);
        int jg0 = jt * 128 + wr * 64 + fr * 16 + ((lane >> 4) << 2);
        us4 pv = *(const us4*)&posb[(size_t)ig * NS + jg0];
#pragma unroll
        for (int r = 0; r < 4; ++r)
          sacc[fr][r] += __expf(acc[fr][fc][r] + bf2f(pv[r]));
      }
  }
#pragma unroll
  for (int m = 1; m <= 8; m <<= 1)
#pragma unroll
    for (int fr = 0; fr < 4; ++fr)
#pragma unroll
      for (int r = 0; r < 4; ++r)
        sacc[fr][r] += __shfl_xor(sacc[fr][r], m, 64);
  if ((lane & 15) == 0){
#pragma unroll
    for (int fr = 0; fr < 4; ++fr)
#pragma unroll
      for (int r = 0; r < 4; ++r)
        sred[wr][wc][fr * 16 + ((lane >> 4) << 2) + r] = sacc[fr][r];
  }
  __syncthreads();
  if (tid < 128){
    int jl = tid;
    sp[((size_t)b * 4 + ih) * NS + jt * 128 + jl] = sred[jl >> 6][0][jl & 63] + sred[jl >> 6][1][jl & 63];
  }
}

// rs[b][j] = 1 / sum_ih sp[b][ih][j]
__global__ void k_rs(const float* sp, float* rs){
  int idx = blockIdx.x * 256 + threadIdx.x;    // 32768 total
  int b = idx >> 12, j = idx & 4095;
  const float* spb = sp + (size_t)b * 4 * NS + j;
  rs[idx] = 1.f / (spb[0] + spb[NS] + spb[2 * NS] + spb[3 * NS]);
}

// ---------------- fused  E = exp(L)/s_j  and  y = g @ E^T ----------------
// 512 threads / 8 waves, i-block 64.
// L-phase roles: jw = wid&3 (4x32 j), iw = wid>>2 (2x32 i): lacc[2 fr(j)][2 fc(i)]
// PV roles:      cw = wid&3 (4x64 c), iw = wid>>2 (2x32 i): yacc[4 cf][2 if]
__global__ __launch_bounds__(512, 4) void k_y(const unsigned short* tp, const unsigned short* posb,
                                              const unsigned short* gb, const float* rs,
                                              unsigned short* yb){
  int b = blockIdx.y, i0 = blockIdx.x * 64;
  int tid = threadIdx.x, wid = tid >> 6, lane = tid & 63;
  int jw = wid & 3, iw = wid >> 2;
  __shared__ unsigned short Th[64 * 264];     // thetaT block, padded rows
  __shared__ unsigned short Aph[2][128 * 32]; // phi k-chunk dbuf
  __shared__ unsigned short El[64 * 136];     // E tile [64 i][136 j pad]
  const unsigned short* tpb = tp + (size_t)b * NS * 512;
#pragma unroll
  for (int t = 0; t < 4; ++t){
    int cid = t * 512 + tid; int row = cid >> 5, ch = cid & 31;
    *(us8*)&Th[row * 264 + ch * 8] = *(const us8*)&tpb[(size_t)(i0 + row) * 512 + 256 + ch * 8];
  }
  f32x4 yacc[4][2];
  {
    f32x4 z = {0.f, 0.f, 0.f, 0.f};
#pragma unroll
    for (int i = 0; i < 4; ++i)
#pragma unroll
      for (int j = 0; j < 2; ++j) yacc[i][j] = z;
  }
  __syncthreads();
  const unsigned short* gbb = gb + (size_t)b * NIC * NS;
  const float* rsb = rs + (size_t)b * NS;
  for (int jt = 0; jt < 32; ++jt){
    int j0 = jt * 128;
    f32x4 lacc[2][2];
    {
      f32x4 z = {0.f, 0.f, 0.f, 0.f};
#pragma unroll
      for (int i = 0; i < 2; ++i)
#pragma unroll
        for (int j = 0; j < 2; ++j) lacc[i][j] = z;
    }
    stageA8(Aph[0], tpb + (size_t)j0 * 512, 512, wid, lane);
    __syncthreads();
    for (int kk = 0; kk < 8; ++kk){
      int cur = kk & 1;
      if (kk < 7) stageA8(Aph[cur ^ 1], tpb + (size_t)j0 * 512 + (kk + 1) * 32, 512, wid, lane);
      bf8 a[2], bbf[2];
#pragma unroll
      for (int f = 0; f < 2; ++f)
        a[f] = *(const bf8*)&Aph[cur][(jw * 32 + f * 16 + (lane & 15)) * 32 + (lane >> 4) * 8];
#pragma unroll
      for (int f = 0; f < 2; ++f)
        bbf[f] = *(const bf8*)&Th[(iw * 32 + f * 16 + (lane & 15)) * 264 + kk * 32 + (lane >> 4) * 8];
#pragma unroll
      for (int i = 0; i < 2; ++i)
#pragma unroll
        for (int j = 0; j < 2; ++j)
          lacc[i][j] = __builtin_amdgcn_mfma_f32_16x16x32_bf16(a[i], bbf[j], lacc[i][j], 0, 0, 0);
      __syncthreads();
    }
    // E-write: E[i][j] = exp(L + pos) * rs[j]
#pragma unroll
    for (int fr = 0; fr < 2; ++fr)
#pragma unroll
      for (int fc = 0; fc < 2; ++fc){
        int il  = iw * 32 + fc * 16 + (lane & 15);
        int jl0 = jw * 32 + fr * 16 + ((lane >> 4) << 2);
        us4 pv = *(const us4*)&posb[(size_t)(i0 + il) * NS + j0 + jl0];
        f32x4 rv = *(const f32x4*)&rsb[j0 + jl0];
        us4 ev;
#pragma unroll
        for (int r = 0; r < 4; ++r)
          ev[r] = f2bf(__expf(lacc[fr][fc][r] + bf2f(pv[r])) * rv[r]);
        *(us4*)&El[il * 136 + jl0] = ev;
      }
    __syncthreads();
    // PV: yacc[c][i] += g frags x E frags over k=j (128)
    __builtin_amdgcn_s_setprio(1);
#pragma unroll
    for (int jk = 0; jk < 4; ++jk){
      bf8 eb[2];
#pragma unroll
      for (int f = 0; f < 2; ++f)
        eb[f] = *(const bf8*)&El[(iw * 32 + f * 16 + (lane & 15)) * 136 + jk * 32 + (lane >> 4) * 8];
#pragma unroll
      for (int cf = 0; cf < 4; ++cf){
        int c = jw * 64 + cf * 16 + (lane & 15);
        bf8 ga = *(const bf8*)&gbb[(size_t)c * NS + j0 + jk * 32 + (lane >> 4) * 8];
#pragma unroll
        for (int f = 0; f < 2; ++f)
          yacc[cf][f] = __builtin_amdgcn_mfma_f32_16x16x32_bf16(ga, eb[f], yacc[cf][f], 0, 0, 0);
      }
    }
    __builtin_amdgcn_s_setprio(0);
  }
  unsigned short* yo = yb + (size_t)b * NS * NIC;
#pragma unroll
  for (int cf = 0; cf < 4; ++cf)
#pragma unroll
    for (int f = 0; f < 2; ++f){
      int c0 = jw * 64 + cf * 16 + ((lane >> 4) << 2);
      int ig = i0 + iw * 32 + f * 16 + (lane & 15);
      us4 v;
#pragma unroll
      for (int r = 0; r < 4; ++r) v[r] = f2bf(yacc[cf][f][r]);
      *(us4*)&yo[(size_t)ig * NIC + c0] = v;
    }
}

// ---------------- mask GEMM + residual ----------------
// out[b][co][n] = sum_ic yb[b][n][ic]*wmb[co][ic] + x   (A = y rows n, B = wm rows co)
__global__ __launch_bounds__(256, 2) void k_out(const unsigned short* yb, const unsigned short* wmb,
                                                const float* xg, float* outg){
  int b = blockIdx.z, cot = blockIdx.y, nt = blockIdx.x;
  int tid = threadIdx.x, wid = tid >> 6, lane = tid & 63, wr = wid >> 1, wc = wid & 1;
  __shared__ unsigned short Ab[2][4096], Bb[2][4096];
  f32x4 acc[4][4]; zero44(acc);
  gemm128<8>(yb + ((size_t)b * NS + nt * 128) * 256, 256,
             wmb + (size_t)(cot * 128) * 256, 256, Ab, Bb, acc, wid, lane);
#pragma unroll
  for (int fr = 0; fr < 4; ++fr)
#pragma unroll
    for (int fc = 0; fc < 4; ++fc){
      int n0 = nt * 128 + wr * 64 + fr * 16 + ((lane >> 4) << 2);
      int co = cot * 128 + wc * 64 + fc * 16 + (lane & 15);
      f32x4 xv = *(const f32x4*)&xg[((size_t)b * NC + co) * NS + n0];
      f32x4 ov = acc[fr][fc] + xv;
      *(f32x4*)&outg[((size_t)b * NC + co) * NS + n0] = ov;
    }
}

extern "C" void kernel_launch(void* const* d_in, const int* in_sizes, int n_in,
                              void* d_out, int out_size, void* d_ws, size_t ws_size,
                              hipStream_t stream){
  const float* x      = (const float*)d_in[0];
  const float* wphi   = (const float*)d_in[1];
  const float* wtheta = (const float*)d_in[2];
  const float* wgf    = (const float*)d_in[3];
  const float* wmf    = (const float*)d_in[4];
  const float* pos    = (const float*)d_in[5];
  const float* pdec   = (const float*)d_in[6];
  float* outg = (float*)d_out;
  char* ws = (char*)d_ws;
  unsigned short* xT   = (unsigned short*)(ws + OFF_XT);
  unsigned short* tp   = (unsigned short*)(ws + OFF_TP);
  unsigned short* posb = (unsigned short*)(ws + OFF_POS);
  unsigned short* gb   = (unsigned short*)(ws + OFF_G);
  float*          rsv  = (float*)(ws + OFF_RS);
  unsigned short* yb   = (unsigned short*)(ws + OFF_Y);
  unsigned short* wtp  = (unsigned short*)(ws + OFF_WTP);
  unsigned short* wgb  = (unsigned short*)(ws + OFF_WG);
  unsigned short* wmb  = (unsigned short*)(ws + OFF_WM);
  float* sp = (float*)(ws + OFF_SP);

  k_prep<<<512, 256, 0, stream>>>(wphi, wtheta, wgf, wmf, wtp, wgb, wmb);
  k_pos<<<8192, 256, 0, stream>>>(pos, posb);
  k_xt<<<dim3(64, 8, 8), 256, 0, stream>>>(x, xT);
  k_tp<<<dim3(32, 4, 8), 256, 0, stream>>>(wtp, xT, tp);
  k_g<<<dim3(32, 2, 8), 256, 0, stream>>>(xT, wgb, pdec, gb);
  k_stats<<<dim3(32, 4, 8), 256, 0, stream>>>(tp, posb, sp);
  k_rs<<<128, 256, 0, stream>>>(sp, rsv);
  k_y<<<dim3(64, 8), 512, 0, stream>>>(tp, posb, gb, rsv, yb);
  k_out<<<dim3(32, 4, 8), 256, 0, stream>>>(yb, wmb, x, outg);
}

// Round 3
// 550.028 us; speedup vs baseline: 1.2115x; 1.2115x over previous
//
#include <hip/hip_runtime.h>

typedef short bf8 __attribute__((ext_vector_type(8)));      // 8 bf16 bit-patterns (4 VGPR) - MFMA A/B frag
typedef float f32x4 __attribute__((ext_vector_type(4)));    // MFMA C/D frag
typedef unsigned short us4 __attribute__((ext_vector_type(4)));
typedef unsigned short us8 __attribute__((ext_vector_type(8)));

#define DEVI __device__ __forceinline__

constexpr int NB = 8, NC = 512, NIC = 256, NS = 4096;   // batch, C, IC, N=H*W

// workspace layout (bytes)
constexpr size_t OFF_XT  = 0;          // xT   [8][4096][512] bf16 (x transposed, n-major)
constexpr size_t OFF_TP  = 33554432;   // tp   [8][4096][512] bf16 (cols 0-255 phiT, 256-511 thetaT)
constexpr size_t OFF_POS = 67108864;   // posb [4096][4096] bf16
constexpr size_t OFF_G   = 100663296;  // gb   [8][256][4096] bf16  (g + pos_dec, unscaled)
constexpr size_t OFF_RS  = 117440512;  // rs   [8][4096] f32  (1/s_j)
constexpr size_t OFF_Y   = 134217728;  // yb   [8][4096][256] bf16
constexpr size_t OFF_WTP = 150994944;  // wtp  [512][512] bf16 (rows 0-255 w_phi, 256-511 w_theta)
constexpr size_t OFF_WG  = 151519232;  // wgb  [256][512] bf16
constexpr size_t OFF_WM  = 151781376;  // wmb  [512][256] bf16
constexpr size_t OFF_SP  = 152043520;  // sp   [8][4][4096] f32 partial column sum-exp

DEVI unsigned short f2bf(float f){
  unsigned u = __float_as_uint(f);
  u += 0x7fffu + ((u >> 16) & 1u);   // RNE
  return (unsigned short)(u >> 16);
}
DEVI float bf2f(unsigned short b){ return __uint_as_float(((unsigned)b) << 16); }

DEVI void gld16(const void* g, void* l){
  __builtin_amdgcn_global_load_lds((const __attribute__((address_space(1))) unsigned int*)g,
                                   (__attribute__((address_space(3))) unsigned int*)l, 16, 0, 0);
}

// stage a [128 rows x 32 cols] bf16 tile, linear LDS, 4 waves (256 threads)
DEVI void stage128x32(unsigned short* dst, const unsigned short* src, int ld, int wid, int lane){
#pragma unroll
  for (int r = 0; r < 2; ++r){
    int instr = wid + r * 4;                 // 8 x 1024B
    int row = instr * 16 + (lane >> 2);
    gld16(src + (size_t)row * ld + (lane & 3) * 8, dst + instr * 512);
  }
}

// stage a [128 j][64 k] bf16 tile (16 KB), XOR-swizzled via pre-swizzled global source.
// physical(row, cb) holds logical (row, cb ^ ((row&7)<<4)); LDS dest stays linear.
DEVI void stagePhi(unsigned short* dst, const unsigned short* src, int wid, int lane){
  int rl = lane >> 3;                                   // row within 8-row group
  int ce = ((lane & 7) << 3) ^ (rl << 3);               // swizzled source col (elems)
#pragma unroll
  for (int it = 0; it < 4; ++it){
    int q = wid + it * 4;                               // wave-uniform instr id 0..15
    gld16(src + (size_t)(q * 8 + rl) * 512 + ce, dst + q * 512);
  }
}

DEVI void zero44(f32x4 (&a)[4][4]){
  f32x4 z = {0.f, 0.f, 0.f, 0.f};
#pragma unroll
  for (int i = 0; i < 4; ++i)
#pragma unroll
    for (int j = 0; j < 4; ++j) a[i][j] = z;
}

// 128x128 tile GEMM, K = NK*32.  A rows = m (stride lda), B rows = n (stride ldb).
// D frag (fr,fc): m = wr*64+fr*16+(lane>>4)*4+reg, n = wc*64+fc*16+(lane&15)
template<int NK>
DEVI void gemm128(const unsigned short* Ag, int lda, const unsigned short* Bg, int ldb,
                  unsigned short (&Ab)[2][4096], unsigned short (&Bb)[2][4096],
                  f32x4 (&acc)[4][4], int wid, int lane)
{
  const int wr = wid >> 1, wc = wid & 1;
  stage128x32(Ab[0], Ag, lda, wid, lane);
  stage128x32(Bb[0], Bg, ldb, wid, lane);
  __syncthreads();
  for (int kk = 0; kk < NK; ++kk){
    int cur = kk & 1;
    if (kk + 1 < NK){
      stage128x32(Ab[cur ^ 1], Ag + (kk + 1) * 32, lda, wid, lane);
      stage128x32(Bb[cur ^ 1], Bg + (kk + 1) * 32, ldb, wid, lane);
    }
    bf8 a[4], b[4];
#pragma unroll
    for (int f = 0; f < 4; ++f){
      a[f] = *(const bf8*)&Ab[cur][(wr * 64 + f * 16 + (lane & 15)) * 32 + (lane >> 4) * 8];
      b[f] = *(const bf8*)&Bb[cur][(wc * 64 + f * 16 + (lane & 15)) * 32 + (lane >> 4) * 8];
    }
#pragma unroll
    for (int i = 0; i < 4; ++i)
#pragma unroll
      for (int j = 0; j < 4; ++j)
        acc[i][j] = __builtin_amdgcn_mfma_f32_16x16x32_bf16(a[i], b[j], acc[i][j], 0, 0, 0);
    __syncthreads();
  }
}

// ---------------- small prep kernels ----------------

__global__ void k_prep(const float* wphi, const float* wtheta, const float* wgf, const float* wmf,
                       unsigned short* wtp, unsigned short* wgb, unsigned short* wmb){
  int idx = (blockIdx.x * 256 + threadIdx.x) * 4;
  const float* src; unsigned short* dst;
  if (idx < 131072)      { src = wphi + idx;            dst = wtp + idx; }
  else if (idx < 262144) { src = wtheta + (idx - 131072); dst = wtp + idx; }
  else if (idx < 393216) { src = wgf + (idx - 262144);  dst = wgb + (idx - 262144); }
  else                   { src = wmf + (idx - 393216);  dst = wmb + (idx - 393216); }
  f32x4 v = *(const f32x4*)src;
  us4 o;
#pragma unroll
  for (int r = 0; r < 4; ++r) o[r] = f2bf(v[r]);
  *(us4*)dst = o;
}

__global__ void k_pos(const float* pos, unsigned short* posb){
  size_t base = ((size_t)blockIdx.x * 256 + threadIdx.x) * 8;
  f32x4 v0 = *(const f32x4*)&pos[base];
  f32x4 v1 = *(const f32x4*)&pos[base + 4];
  us8 o;
#pragma unroll
  for (int r = 0; r < 4; ++r){ o[r] = f2bf(v0[r]); o[r + 4] = f2bf(v1[r]); }
  *(us8*)&posb[base] = o;
}

// x [b][512][4096] f32 -> xT [b][4096][512] bf16
__global__ void k_xt(const float* x, unsigned short* xT){
  int b = blockIdx.z, ct = blockIdx.y, nt = blockIdx.x;
  __shared__ float t[64][65];
  int tid = threadIdx.x;
  int c0 = ct * 64, n0 = nt * 64;
  const float* xp = x + (size_t)b * NC * NS;
#pragma unroll
  for (int it = 0; it < 16; ++it){
    int idx = it * 256 + tid; int r = idx >> 6, cc = idx & 63;
    t[r][cc] = xp[(size_t)(c0 + r) * NS + n0 + cc];
  }
  __syncthreads();
  unsigned short* xo = xT + (size_t)b * NS * NC;
#pragma unroll
  for (int it = 0; it < 16; ++it){
    int idx = it * 256 + tid; int r = idx >> 6, cc = idx & 63;
    xo[(size_t)(n0 + r) * NC + c0 + cc] = f2bf(t[cc][r]);
  }
}

// ---------------- projection GEMMs ----------------

// tp[b][n][o] = sum_c wtp[o][c] * xT[b][n][c]   (A = wtp rows o, B = xT rows n)
__global__ __launch_bounds__(256, 2) void k_tp(const unsigned short* wtp, const unsigned short* xT,
                                               unsigned short* tp){
  int b = blockIdx.z, ot = blockIdx.y, nt = blockIdx.x;
  int tid = threadIdx.x, wid = tid >> 6, lane = tid & 63, wr = wid >> 1, wc = wid & 1;
  __shared__ unsigned short Ab[2][4096], Bb[2][4096];
  f32x4 acc[4][4]; zero44(acc);
  gemm128<16>(wtp + (size_t)(ot * 128) * 512, 512,
              xT + ((size_t)b * NS + nt * 128) * 512, 512, Ab, Bb, acc, wid, lane);
  unsigned short* out = tp + (size_t)b * NS * 512;
#pragma unroll
  for (int fr = 0; fr < 4; ++fr)
#pragma unroll
    for (int fc = 0; fc < 4; ++fc){
      int o0 = ot * 128 + wr * 64 + fr * 16 + ((lane >> 4) << 2);
      int n  = nt * 128 + wc * 64 + fc * 16 + (lane & 15);
      us4 v;
#pragma unroll
      for (int r = 0; r < 4; ++r) v[r] = f2bf(acc[fr][fc][r]);
      *(us4*)&out[(size_t)n * 512 + o0] = v;
    }
}

// gb[b][o][n] = sum_c xT[b][n][c]*wgb[o][c] + pdec[o][n]   (A = xT rows n, B = wgb rows o)
__global__ __launch_bounds__(256, 2) void k_g(const unsigned short* xT, const unsigned short* wgb,
                                              const float* pdec, unsigned short* gb){
  int b = blockIdx.z, ot = blockIdx.y, nt = blockIdx.x;
  int tid = threadIdx.x, wid = tid >> 6, lane = tid & 63, wr = wid >> 1, wc = wid & 1;
  __shared__ unsigned short Ab[2][4096], Bb[2][4096];
  f32x4 acc[4][4]; zero44(acc);
  gemm128<16>(xT + ((size_t)b * NS + nt * 128) * 512, 512,
              wgb + (size_t)(ot * 128) * 512, 512, Ab, Bb, acc, wid, lane);
#pragma unroll
  for (int fr = 0; fr < 4; ++fr)
#pragma unroll
    for (int fc = 0; fc < 4; ++fc){
      int n0 = nt * 128 + wr * 64 + fr * 16 + ((lane >> 4) << 2);
      int o  = ot * 128 + wc * 64 + fc * 16 + (lane & 15);
      f32x4 pd = *(const f32x4*)&pdec[(size_t)o * NS + n0];
      us4 v;
#pragma unroll
      for (int r = 0; r < 4; ++r) v[r] = f2bf(acc[fr][fc][r] + pd[r]);
      *(us4*)&gb[((size_t)b * NIC + o) * NS + n0] = v;
    }
}

// ---------------- softmax denominators ----------------
// Lt[j][i] = sum_c phiT[j][c]*thetaT[i][c]; sp[b][ih][j] = sum_{i in chunk} exp(Lt + pos[i][j])
__global__ __launch_bounds__(256, 2) void k_stats(const unsigned short* tp, const unsigned short* posb,
                                                  float* sp){
  int b = blockIdx.z, ih = blockIdx.y, jt = blockIdx.x;
  int tid = threadIdx.x, wid = tid >> 6, lane = tid & 63, wr = wid >> 1, wc = wid & 1;
  __shared__ unsigned short Ab[2][4096], Bb[2][4096];
  __shared__ float sred[2][2][64];
  float sacc[4][4];   // [fr][r] -> local j
#pragma unroll
  for (int i = 0; i < 4; ++i)
#pragma unroll
    for (int j = 0; j < 4; ++j) sacc[i][j] = 0.f;
  const unsigned short* tpb = tp + (size_t)b * NS * 512;
  const unsigned short* Ag = tpb + (size_t)(jt * 128) * 512;         // phiT rows j
  for (int it8 = 0; it8 < 8; ++it8){
    int i0 = (ih * 8 + it8) * 128;
    const unsigned short* Bg = tpb + (size_t)i0 * 512 + 256;         // thetaT rows i
    f32x4 acc[4][4]; zero44(acc);
    gemm128<8>(Ag, 512, Bg, 512, Ab, Bb, acc, wid, lane);
#pragma unroll
    for (int fr = 0; fr < 4; ++fr)
#pragma unroll
      for (int fc = 0; fc < 4; ++fc){
        int ig  = i0 + wc * 64 + fc * 16 + (lane & 15);
        int jg0 = jt * 128 + wr * 64 + fr * 16 + ((lane >> 4) << 2);
        us4 pv = *(const us4*)&posb[(size_t)ig * NS + jg0];
#pragma unroll
        for (int r = 0; r < 4; ++r)
          sacc[fr][r] += __expf(acc[fr][fc][r] + bf2f(pv[r]));
      }
  }
#pragma unroll
  for (int m = 1; m <= 8; m <<= 1)
#pragma unroll
    for (int fr = 0; fr < 4; ++fr)
#pragma unroll
      for (int r = 0; r < 4; ++r)
        sacc[fr][r] += __shfl_xor(sacc[fr][r], m, 64);
  if ((lane & 15) == 0){
#pragma unroll
    for (int fr = 0; fr < 4; ++fr)
#pragma unroll
      for (int r = 0; r < 4; ++r)
        sred[wr][wc][fr * 16 + ((lane >> 4) << 2) + r] = sacc[fr][r];
  }
  __syncthreads();
  if (tid < 128){
    int jl = tid;
    sp[((size_t)b * 4 + ih) * NS + jt * 128 + jl] = sred[jl >> 6][0][jl & 63] + sred[jl >> 6][1][jl & 63];
  }
}

// rs[b][j] = 1 / sum_ih sp[b][ih][j]
__global__ void k_rs(const float* sp, float* rs){
  int idx = blockIdx.x * 256 + threadIdx.x;    // 32768 total
  int b = idx >> 12, j = idx & 4095;
  const float* spb = sp + (size_t)b * 4 * NS + j;
  rs[idx] = 1.f / (spb[0] + spb[NS] + spb[2 * NS] + spb[3 * NS]);
}

// ---------------- fused  E = exp(L+pos)*rs_j  and  y = g @ E^T ----------------
// 256 threads / 4 waves, i-block 64, j-tile 128, BK=64, 5 barriers per jt.
// L roles: wave owns 32 j (wid*32), all waves cover 64 i -> lacc[2 fr(j)][4 fc(i)]
// PV roles: wave owns 64 c (wid*64), all waves cover 64 i -> yacc[4 cf][4 if]
__global__ __launch_bounds__(256, 2) void k_y(const unsigned short* tp, const unsigned short* posb,
                                              const unsigned short* gb, const float* rs,
                                              unsigned short* yb){
  int b = blockIdx.y, i0 = blockIdx.x * 64;
  int tid = threadIdx.x, wid = tid >> 6, lane = tid & 63;
  __shared__ unsigned short Th[64 * 256];      // theta [64 i][256 c], XOR-swizzled, 32 KB
  __shared__ unsigned short Aph[2][128 * 64];  // phi [128 j][64 k] dbuf, swizzled, 32 KB
  __shared__ unsigned short El[64 * 128];      // E [64 i][128 j], XOR-swizzled, 16 KB
  const unsigned short* tpb = tp + (size_t)b * NS * 512;

  // theta -> swizzled Th: physical(row, cb) = logical cb ^ ((row&7)<<4)
#pragma unroll
  for (int t = 0; t < 8; ++t){
    int cid = t * 256 + tid;                   // 2048 x 16B chunks
    int row = cid >> 5, ch = cid & 31;
    int dstb = row * 512 + ((ch * 16) ^ ((row & 7) << 4));
    *(us8*)((char*)Th + dstb) = *(const us8*)&tpb[(size_t)(i0 + row) * 512 + 256 + ch * 8];
  }
  f32x4 yacc[4][4]; zero44(yacc);              // [cf][if]
  stagePhi(Aph[0], tpb, wid, lane);            // jt=0, ph=0
  __syncthreads();

  const unsigned short* gbb = gb + (size_t)b * NIC * NS;
  const float* rsb = rs + (size_t)b * NS;

  for (int jt = 0; jt < 32; ++jt){
    int j0 = jt * 128;
    const unsigned short* phiBase = tpb + (size_t)j0 * 512;
    f32x4 lacc[2][4];
    {
      f32x4 z = {0.f, 0.f, 0.f, 0.f};
#pragma unroll
      for (int i = 0; i < 2; ++i)
#pragma unroll
        for (int j = 0; j < 4; ++j) lacc[i][j] = z;
    }
    // ---- L phases: 4 x (BK=64, 16 MFMA) ----
#pragma unroll
    for (int ph = 0; ph < 4; ++ph){
      int cur = ph & 1;
      if (ph < 3) stagePhi(Aph[cur ^ 1], phiBase + (ph + 1) * 64, wid, lane);
      bf8 a[2][2], bt[2][4];
#pragma unroll
      for (int ks = 0; ks < 2; ++ks){
#pragma unroll
        for (int f = 0; f < 2; ++f){
          int r = wid * 32 + f * 16 + (lane & 15);
          int lb = ks * 64 + ((lane >> 4) << 4);
          a[ks][f] = *(const bf8*)((char*)Aph[cur] + r * 128 + (lb ^ ((r & 7) << 4)));
        }
#pragma unroll
        for (int f = 0; f < 4; ++f){
          int ti = f * 16 + (lane & 15);
          int tb = ph * 128 + ks * 64 + ((lane >> 4) << 4);
          bt[ks][f] = *(const bf8*)((char*)Th + ti * 512 + (tb ^ ((ti & 7) << 4)));
        }
      }
      __builtin_amdgcn_s_setprio(1);
#pragma unroll
      for (int ks = 0; ks < 2; ++ks)
#pragma unroll
        for (int fr = 0; fr < 2; ++fr)
#pragma unroll
          for (int fc = 0; fc < 4; ++fc)
            lacc[fr][fc] = __builtin_amdgcn_mfma_f32_16x16x32_bf16(a[ks][fr], bt[ks][fc], lacc[fr][fc], 0, 0, 0);
      __builtin_amdgcn_s_setprio(0);
      if (ph < 3) __syncthreads();
    }
    // ---- E-write: E[i][j] = exp(L+pos)*rs[j] -> swizzled El ----
#pragma unroll
    for (int fr = 0; fr < 2; ++fr)
#pragma unroll
      for (int fc = 0; fc < 4; ++fc){
        int il = fc * 16 + (lane & 15);
        int jl = wid * 32 + fr * 16 + ((lane >> 4) << 2);
        us4 pv = *(const us4*)&posb[(size_t)(i0 + il) * NS + j0 + jl];
        f32x4 rv = *(const f32x4*)&rsb[j0 + jl];
        us4 ev;
#pragma unroll
        for (int r = 0; r < 4; ++r)
          ev[r] = f2bf(__expf(lacc[fr][fc][r] + bf2f(pv[r])) * rv[r]);
        *(us4*)((char*)El + il * 256 + ((jl * 2) ^ ((il & 7) << 4))) = ev;
      }
    __syncthreads();                            // El visible; Aph reads done
    if (jt < 31) stagePhi(Aph[0], tpb + (size_t)(j0 + 128) * 512, wid, lane);  // overlap with PV
    // ---- PV: yacc[c][i] += g x E over k=j (128) ----
#pragma unroll
    for (int jk = 0; jk < 4; ++jk){
      bf8 eb[4];
#pragma unroll
      for (int f = 0; f < 4; ++f){
        int ei = f * 16 + (lane & 15);
        int ebt = jk * 64 + ((lane >> 4) << 4);
        eb[f] = *(const bf8*)((char*)El + ei * 256 + (ebt ^ ((ei & 7) << 4)));
      }
      __builtin_amdgcn_s_setprio(1);
#pragma unroll
      for (int cf = 0; cf < 4; ++cf){
        int c = wid * 64 + cf * 16 + (lane & 15);
        bf8 ga = *(const bf8*)&gbb[(size_t)c * NS + j0 + jk * 32 + (lane >> 4) * 8];
#pragma unroll
        for (int f = 0; f < 4; ++f)
          yacc[cf][f] = __builtin_amdgcn_mfma_f32_16x16x32_bf16(ga, eb[f], yacc[cf][f], 0, 0, 0);
      }
      __builtin_amdgcn_s_setprio(0);
    }
    __syncthreads();                            // El reads done; next-jt Aph[0] staged
  }
  unsigned short* yo = yb + (size_t)b * NS * NIC;
#pragma unroll
  for (int cf = 0; cf < 4; ++cf)
#pragma unroll
    for (int f = 0; f < 4; ++f){
      int c0 = wid * 64 + cf * 16 + ((lane >> 4) << 2);
      int ig = i0 + f * 16 + (lane & 15);
      us4 v;
#pragma unroll
      for (int r = 0; r < 4; ++r) v[r] = f2bf(yacc[cf][f][r]);
      *(us4*)&yo[(size_t)ig * NIC + c0] = v;
    }
}

// ---------------- mask GEMM + residual ----------------
// out[b][co][n] = sum_ic yb[b][n][ic]*wmb[co][ic] + x   (A = y rows n, B = wm rows co)
__global__ __launch_bounds__(256, 2) void k_out(const unsigned short* yb, const unsigned short* wmb,
                                                const float* xg, float* outg){
  int b = blockIdx.z, cot = blockIdx.y, nt = blockIdx.x;
  int tid = threadIdx.x, wid = tid >> 6, lane = tid & 63, wr = wid >> 1, wc = wid & 1;
  __shared__ unsigned short Ab[2][4096], Bb[2][4096];
  f32x4 acc[4][4]; zero44(acc);
  gemm128<8>(yb + ((size_t)b * NS + nt * 128) * 256, 256,
             wmb + (size_t)(cot * 128) * 256, 256, Ab, Bb, acc, wid, lane);
#pragma unroll
  for (int fr = 0; fr < 4; ++fr)
#pragma unroll
    for (int fc = 0; fc < 4; ++fc){
      int n0 = nt * 128 + wr * 64 + fr * 16 + ((lane >> 4) << 2);
      int co = cot * 128 + wc * 64 + fc * 16 + (lane & 15);
      f32x4 xv = *(const f32x4*)&xg[((size_t)b * NC + co) * NS + n0];
      f32x4 ov = acc[fr][fc] + xv;
      *(f32x4*)&outg[((size_t)b * NC + co) * NS + n0] = ov;
    }
}

extern "C" void kernel_launch(void* const* d_in, const int* in_sizes, int n_in,
                              void* d_out, int out_size, void* d_ws, size_t ws_size,
                              hipStream_t stream){
  const float* x      = (const float*)d_in[0];
  const float* wphi   = (const float*)d_in[1];
  const float* wtheta = (const float*)d_in[2];
  const float* wgf    = (const float*)d_in[3];
  const float* wmf    = (const float*)d_in[4];
  const float* pos    = (const float*)d_in[5];
  const float* pdec   = (const float*)d_in[6];
  float* outg = (float*)d_out;
  char* ws = (char*)d_ws;
  unsigned short* xT   = (unsigned short*)(ws + OFF_XT);
  unsigned short* tp   = (unsigned short*)(ws + OFF_TP);
  unsigned short* posb = (unsigned short*)(ws + OFF_POS);
  unsigned short* gb   = (unsigned short*)(ws + OFF_G);
  float*          rsv  = (float*)(ws + OFF_RS);
  unsigned short* yb   = (unsigned short*)(ws + OFF_Y);
  unsigned short* wtp  = (unsigned short*)(ws + OFF_WTP);
  unsigned short* wgb  = (unsigned short*)(ws + OFF_WG);
  unsigned short* wmb  = (unsigned short*)(ws + OFF_WM);
  float* sp = (float*)(ws + OFF_SP);

  k_prep<<<512, 256, 0, stream>>>(wphi, wtheta, wgf, wmf, wtp, wgb, wmb);
  k_pos<<<8192, 256, 0, stream>>>(pos, posb);
  k_xt<<<dim3(64, 8, 8), 256, 0, stream>>>(x, xT);
  k_tp<<<dim3(32, 4, 8), 256, 0, stream>>>(wtp, xT, tp);
  k_g<<<dim3(32, 2, 8), 256, 0, stream>>>(xT, wgb, pdec, gb);
  k_stats<<<dim3(32, 4, 8), 256, 0, stream>>>(tp, posb, sp);
  k_rs<<<128, 256, 0, stream>>>(sp, rsv);
  k_y<<<dim3(64, 8), 256, 0, stream>>>(tp, posb, gb, rsv, yb);
  k_out<<<dim3(32, 4, 8), 256, 0, stream>>>(yb, wmb, x, outg);
}

// Round 4
// 515.172 us; speedup vs baseline: 1.2934x; 1.0677x over previous
//
#include <hip/hip_runtime.h>

typedef short bf8 __attribute__((ext_vector_type(8)));      // 8 bf16 bit-patterns (4 VGPR) - MFMA A/B frag
typedef float f32x4 __attribute__((ext_vector_type(4)));    // MFMA C/D frag
typedef unsigned short us4 __attribute__((ext_vector_type(4)));
typedef unsigned short us8 __attribute__((ext_vector_type(8)));

#define DEVI __device__ __forceinline__

constexpr int NB = 8, NC = 512, NIC = 256, NS = 4096;   // batch, C, IC, N=H*W

// workspace layout (bytes)
constexpr size_t OFF_XT  = 0;          // xT   [8][4096][512] bf16 (x transposed, n-major)
constexpr size_t OFF_TP  = 33554432;   // tp   [8][4096][512] bf16 (cols 0-255 phiT, 256-511 thetaT)
constexpr size_t OFF_POS = 67108864;   // posb [4096][4096] bf16
constexpr size_t OFF_G   = 100663296;  // gb   [8][256][4096] bf16  (g + pos_dec, unscaled)
constexpr size_t OFF_RS  = 117440512;  // rs   [8][4096] f32  (1/s_j)
constexpr size_t OFF_Y   = 134217728;  // yb   [8][4096][256] bf16
constexpr size_t OFF_WTP = 150994944;  // wtp  [512][512] bf16 (rows 0-255 w_phi, 256-511 w_theta)
constexpr size_t OFF_WG  = 151519232;  // wgb  [256][512] bf16
constexpr size_t OFF_WM  = 151781376;  // wmb  [512][256] bf16
constexpr size_t OFF_SP  = 152043520;  // sp   [8][4][4096] f32 partial column sum-exp

DEVI unsigned short f2bf(float f){
  unsigned u = __float_as_uint(f);
  u += 0x7fffu + ((u >> 16) & 1u);   // RNE
  return (unsigned short)(u >> 16);
}
DEVI float bf2f(unsigned short b){ return __uint_as_float(((unsigned)b) << 16); }

DEVI void gld16(const void* g, void* l){
  __builtin_amdgcn_global_load_lds((const __attribute__((address_space(1))) unsigned int*)g,
                                   (__attribute__((address_space(3))) unsigned int*)l, 16, 0, 0);
}

// stage a [128 rows x 64 cols] bf16 tile (16 KB), XOR-swizzled via pre-swizzled global source.
// physical(row, 16B-chunk c) holds logical chunk c ^ (row&7); LDS dest stays linear (rule #21).
DEVI void stageT(unsigned short* dst, const unsigned short* src, int ld, int wid, int lane){
  int rl = lane >> 3;                                   // row within 8-row group
  int ce = ((lane & 7) << 3) ^ (rl << 3);               // swizzled source col (elems)
#pragma unroll
  for (int it = 0; it < 4; ++it){
    int q = wid + it * 4;                               // wave-uniform instr id 0..15
    gld16(src + (size_t)(q * 8 + rl) * ld + ce, dst + q * 512);
  }
}

DEVI void zero44(f32x4 (&a)[4][4]){
  f32x4 z = {0.f, 0.f, 0.f, 0.f};
#pragma unroll
  for (int i = 0; i < 4; ++i)
#pragma unroll
    for (int j = 0; j < 4; ++j) a[i][j] = z;
}

// 128x128 tile GEMM, K = NK64*64, BK=64, swizzled LDS (conflict-free ds_read_b128),
// 1 barrier per BK=64. A rows = m (stride lda), B rows = n (stride ldb).
// D frag (fr,fc): m = wr*64+fr*16+(lane>>4)*4+reg, n = wc*64+fc*16+(lane&15)
template<int NK64>
DEVI void gemm128v(const unsigned short* Ag, int lda, const unsigned short* Bg, int ldb,
                   unsigned short (&As)[2][8192], unsigned short (&Bs)[2][8192],
                   f32x4 (&acc)[4][4], int wid, int lane)
{
  const int wr = wid >> 1, wc = wid & 1;
  stageT(As[0], Ag, lda, wid, lane);
  stageT(Bs[0], Bg, ldb, wid, lane);
  __syncthreads();
  for (int kt = 0; kt < NK64; ++kt){
    int cur = kt & 1;
    if (kt + 1 < NK64){
      stageT(As[cur ^ 1], Ag + (kt + 1) * 64, lda, wid, lane);
      stageT(Bs[cur ^ 1], Bg + (kt + 1) * 64, ldb, wid, lane);
    }
    bf8 a[2][4], b[2][4];
#pragma unroll
    for (int ks = 0; ks < 2; ++ks){
      int cb = ks * 64 + ((lane >> 4) << 4);
#pragma unroll
      for (int f = 0; f < 4; ++f){
        int rA = wr * 64 + f * 16 + (lane & 15);
        a[ks][f] = *(const bf8*)((char*)As[cur] + rA * 128 + (cb ^ ((rA & 7) << 4)));
        int rB = wc * 64 + f * 16 + (lane & 15);
        b[ks][f] = *(const bf8*)((char*)Bs[cur] + rB * 128 + (cb ^ ((rB & 7) << 4)));
      }
    }
    __builtin_amdgcn_s_setprio(1);
#pragma unroll
    for (int ks = 0; ks < 2; ++ks)
#pragma unroll
      for (int i = 0; i < 4; ++i)
#pragma unroll
        for (int j = 0; j < 4; ++j)
          acc[i][j] = __builtin_amdgcn_mfma_f32_16x16x32_bf16(a[ks][i], b[ks][j], acc[i][j], 0, 0, 0);
    __builtin_amdgcn_s_setprio(0);
    __syncthreads();
  }
}

// ---------------- small prep kernels ----------------

__global__ void k_prep(const float* wphi, const float* wtheta, const float* wgf, const float* wmf,
                       unsigned short* wtp, unsigned short* wgb, unsigned short* wmb){
  int idx = (blockIdx.x * 256 + threadIdx.x) * 4;
  const float* src; unsigned short* dst;
  if (idx < 131072)      { src = wphi + idx;            dst = wtp + idx; }
  else if (idx < 262144) { src = wtheta + (idx - 131072); dst = wtp + idx; }
  else if (idx < 393216) { src = wgf + (idx - 262144);  dst = wgb + (idx - 262144); }
  else                   { src = wmf + (idx - 393216);  dst = wmb + (idx - 393216); }
  f32x4 v = *(const f32x4*)src;
  us4 o;
#pragma unroll
  for (int r = 0; r < 4; ++r) o[r] = f2bf(v[r]);
  *(us4*)dst = o;
}

__global__ void k_pos(const float* pos, unsigned short* posb){
  size_t base = ((size_t)blockIdx.x * 256 + threadIdx.x) * 8;
  f32x4 v0 = *(const f32x4*)&pos[base];
  f32x4 v1 = *(const f32x4*)&pos[base + 4];
  us8 o;
#pragma unroll
  for (int r = 0; r < 4; ++r){ o[r] = f2bf(v0[r]); o[r + 4] = f2bf(v1[r]); }
  *(us8*)&posb[base] = o;
}

// x [b][512][4096] f32 -> xT [b][4096][512] bf16
__global__ void k_xt(const float* x, unsigned short* xT){
  int b = blockIdx.z, ct = blockIdx.y, nt = blockIdx.x;
  __shared__ float t[64][65];
  int tid = threadIdx.x;
  int c0 = ct * 64, n0 = nt * 64;
  const float* xp = x + (size_t)b * NC * NS;
#pragma unroll
  for (int it = 0; it < 16; ++it){
    int idx = it * 256 + tid; int r = idx >> 6, cc = idx & 63;
    t[r][cc] = xp[(size_t)(c0 + r) * NS + n0 + cc];
  }
  __syncthreads();
  unsigned short* xo = xT + (size_t)b * NS * NC;
#pragma unroll
  for (int it = 0; it < 16; ++it){
    int idx = it * 256 + tid; int r = idx >> 6, cc = idx & 63;
    xo[(size_t)(n0 + r) * NC + c0 + cc] = f2bf(t[cc][r]);
  }
}

// ---------------- projection GEMMs ----------------

// tp[b][n][o] = sum_c wtp[o][c] * xT[b][n][c]   (A = wtp rows o, B = xT rows n)
__global__ __launch_bounds__(256, 2) void k_tp(const unsigned short* wtp, const unsigned short* xT,
                                               unsigned short* tp){
  int b = blockIdx.z, ot = blockIdx.y, nt = blockIdx.x;
  int tid = threadIdx.x, wid = tid >> 6, lane = tid & 63, wr = wid >> 1, wc = wid & 1;
  __shared__ unsigned short As[2][8192], Bs[2][8192];
  f32x4 acc[4][4]; zero44(acc);
  gemm128v<8>(wtp + (size_t)(ot * 128) * 512, 512,
              xT + ((size_t)b * NS + nt * 128) * 512, 512, As, Bs, acc, wid, lane);
  unsigned short* out = tp + (size_t)b * NS * 512;
#pragma unroll
  for (int fr = 0; fr < 4; ++fr)
#pragma unroll
    for (int fc = 0; fc < 4; ++fc){
      int o0 = ot * 128 + wr * 64 + fr * 16 + ((lane >> 4) << 2);
      int n  = nt * 128 + wc * 64 + fc * 16 + (lane & 15);
      us4 v;
#pragma unroll
      for (int r = 0; r < 4; ++r) v[r] = f2bf(acc[fr][fc][r]);
      *(us4*)&out[(size_t)n * 512 + o0] = v;
    }
}

// gb[b][o][n] = sum_c xT[b][n][c]*wgb[o][c] + pdec[o][n]   (A = xT rows n, B = wgb rows o)
__global__ __launch_bounds__(256, 2) void k_g(const unsigned short* xT, const unsigned short* wgb,
                                              const float* pdec, unsigned short* gb){
  int b = blockIdx.z, ot = blockIdx.y, nt = blockIdx.x;
  int tid = threadIdx.x, wid = tid >> 6, lane = tid & 63, wr = wid >> 1, wc = wid & 1;
  __shared__ unsigned short As[2][8192], Bs[2][8192];
  f32x4 acc[4][4]; zero44(acc);
  gemm128v<8>(xT + ((size_t)b * NS + nt * 128) * 512, 512,
              wgb + (size_t)(ot * 128) * 512, 512, As, Bs, acc, wid, lane);
#pragma unroll
  for (int fr = 0; fr < 4; ++fr)
#pragma unroll
    for (int fc = 0; fc < 4; ++fc){
      int n0 = nt * 128 + wr * 64 + fr * 16 + ((lane >> 4) << 2);
      int o  = ot * 128 + wc * 64 + fc * 16 + (lane & 15);
      f32x4 pd = *(const f32x4*)&pdec[(size_t)o * NS + n0];
      us4 v;
#pragma unroll
      for (int r = 0; r < 4; ++r) v[r] = f2bf(acc[fr][fc][r] + pd[r]);
      *(us4*)&gb[((size_t)b * NIC + o) * NS + n0] = v;
    }
}

// ---------------- softmax denominators ----------------
// Lt[j][i] = sum_c phiT[j][c]*thetaT[i][c]; sp[b][ih][j] = sum_{i in chunk} exp(Lt + pos[i][j])
__global__ __launch_bounds__(256, 2) void k_stats(const unsigned short* tp, const unsigned short* posb,
                                                  float* sp){
  int b = blockIdx.z, ih = blockIdx.y, jt = blockIdx.x;
  int tid = threadIdx.x, wid = tid >> 6, lane = tid & 63, wr = wid >> 1, wc = wid & 1;
  __shared__ unsigned short As[2][8192], Bs[2][8192];
  __shared__ float sred[2][2][64];
  float sacc[4][4];   // [fr][r] -> local j
#pragma unroll
  for (int i = 0; i < 4; ++i)
#pragma unroll
    for (int j = 0; j < 4; ++j) sacc[i][j] = 0.f;
  const unsigned short* tpb = tp + (size_t)b * NS * 512;
  const unsigned short* Ag = tpb + (size_t)(jt * 128) * 512;         // phiT rows j
  for (int it8 = 0; it8 < 8; ++it8){
    int i0 = (ih * 8 + it8) * 128;
    const unsigned short* Bg = tpb + (size_t)i0 * 512 + 256;         // thetaT rows i
    f32x4 acc[4][4]; zero44(acc);
    gemm128v<4>(Ag, 512, Bg, 512, As, Bs, acc, wid, lane);
#pragma unroll
    for (int fr = 0; fr < 4; ++fr)
#pragma unroll
      for (int fc = 0; fc < 4; ++fc){
        int ig  = i0 + wc * 64 + fc * 16 + (lane & 15);
        int jg0 = jt * 128 + wr * 64 + fr * 16 + ((lane >> 4) << 2);
        us4 pv = *(const us4*)&posb[(size_t)ig * NS + jg0];
#pragma unroll
        for (int r = 0; r < 4; ++r)
          sacc[fr][r] += __expf(acc[fr][fc][r] + bf2f(pv[r]));
      }
  }
#pragma unroll
  for (int m = 1; m <= 8; m <<= 1)
#pragma unroll
    for (int fr = 0; fr < 4; ++fr)
#pragma unroll
      for (int r = 0; r < 4; ++r)
        sacc[fr][r] += __shfl_xor(sacc[fr][r], m, 64);
  if ((lane & 15) == 0){
#pragma unroll
    for (int fr = 0; fr < 4; ++fr)
#pragma unroll
      for (int r = 0; r < 4; ++r)
        sred[wr][wc][fr * 16 + ((lane >> 4) << 2) + r] = sacc[fr][r];
  }
  __syncthreads();
  if (tid < 128){
    int jl = tid;
    sp[((size_t)b * 4 + ih) * NS + jt * 128 + jl] = sred[jl >> 6][0][jl & 63] + sred[jl >> 6][1][jl & 63];
  }
}

// rs[b][j] = 1 / sum_ih sp[b][ih][j]
__global__ void k_rs(const float* sp, float* rs){
  int idx = blockIdx.x * 256 + threadIdx.x;    // 32768 total
  int b = idx >> 12, j = idx & 4095;
  const float* spb = sp + (size_t)b * 4 * NS + j;
  rs[idx] = 1.f / (spb[0] + spb[NS] + spb[2 * NS] + spb[3 * NS]);
}

// ---------------- fused  E = exp(L+pos)*rs_j  and  y = g @ E^T ----------------
// 256 threads / 4 waves, i-block 64, j-tile 128, BK=64, 5 barriers per jt.
// L roles: wave owns 32 j (wid*32), all waves cover 64 i -> lacc[2 fr(j)][4 fc(i)]
// PV roles: wave owns 64 c (wid*64), all waves cover 64 i -> yacc[4 cf][4 if]
__global__ __launch_bounds__(256, 2) void k_y(const unsigned short* tp, const unsigned short* posb,
                                              const unsigned short* gb, const float* rs,
                                              unsigned short* yb){
  int b = blockIdx.y, i0 = blockIdx.x * 64;
  int tid = threadIdx.x, wid = tid >> 6, lane = tid & 63;
  __shared__ unsigned short Th[64 * 256];      // theta [64 i][256 c], XOR-swizzled, 32 KB
  __shared__ unsigned short Aph[2][128 * 64];  // phi [128 j][64 k] dbuf, swizzled, 32 KB
  __shared__ unsigned short El[64 * 128];      // E [64 i][128 j], XOR-swizzled, 16 KB
  const unsigned short* tpb = tp + (size_t)b * NS * 512;

  // theta -> swizzled Th: physical(row, cb) = logical cb ^ ((row&7)<<4)
#pragma unroll
  for (int t = 0; t < 8; ++t){
    int cid = t * 256 + tid;                   // 2048 x 16B chunks
    int row = cid >> 5, ch = cid & 31;
    int dstb = row * 512 + ((ch * 16) ^ ((row & 7) << 4));
    *(us8*)((char*)Th + dstb) = *(const us8*)&tpb[(size_t)(i0 + row) * 512 + 256 + ch * 8];
  }
  f32x4 yacc[4][4]; zero44(yacc);              // [cf][if]
  stageT(Aph[0], tpb, 512, wid, lane);         // jt=0, ph=0
  __syncthreads();

  const unsigned short* gbb = gb + (size_t)b * NIC * NS;
  const float* rsb = rs + (size_t)b * NS;

  for (int jt = 0; jt < 32; ++jt){
    int j0 = jt * 128;
    const unsigned short* phiBase = tpb + (size_t)j0 * 512;
    f32x4 lacc[2][4];
    {
      f32x4 z = {0.f, 0.f, 0.f, 0.f};
#pragma unroll
      for (int i = 0; i < 2; ++i)
#pragma unroll
        for (int j = 0; j < 4; ++j) lacc[i][j] = z;
    }
    // ---- L phases: 4 x (BK=64, 16 MFMA) ----
#pragma unroll
    for (int ph = 0; ph < 4; ++ph){
      int cur = ph & 1;
      if (ph < 3) stageT(Aph[cur ^ 1], phiBase + (ph + 1) * 64, 512, wid, lane);
      bf8 a[2][2], bt[2][4];
#pragma unroll
      for (int ks = 0; ks < 2; ++ks){
#pragma unroll
        for (int f = 0; f < 2; ++f){
          int r = wid * 32 + f * 16 + (lane & 15);
          int lb = ks * 64 + ((lane >> 4) << 4);
          a[ks][f] = *(const bf8*)((char*)Aph[cur] + r * 128 + (lb ^ ((r & 7) << 4)));
        }
#pragma unroll
        for (int f = 0; f < 4; ++f){
          int ti = f * 16 + (lane & 15);
          int tb = ph * 128 + ks * 64 + ((lane >> 4) << 4);
          bt[ks][f] = *(const bf8*)((char*)Th + ti * 512 + (tb ^ ((ti & 7) << 4)));
        }
      }
      __builtin_amdgcn_s_setprio(1);
#pragma unroll
      for (int ks = 0; ks < 2; ++ks)
#pragma unroll
        for (int fr = 0; fr < 2; ++fr)
#pragma unroll
          for (int fc = 0; fc < 4; ++fc)
            lacc[fr][fc] = __builtin_amdgcn_mfma_f32_16x16x32_bf16(a[ks][fr], bt[ks][fc], lacc[fr][fc], 0, 0, 0);
      __builtin_amdgcn_s_setprio(0);
      if (ph < 3) __syncthreads();
    }
    // ---- E-write: E[i][j] = exp(L+pos)*rs[j] -> swizzled El ----
#pragma unroll
    for (int fr = 0; fr < 2; ++fr)
#pragma unroll
      for (int fc = 0; fc < 4; ++fc){
        int il = fc * 16 + (lane & 15);
        int jl = wid * 32 + fr * 16 + ((lane >> 4) << 2);
        us4 pv = *(const us4*)&posb[(size_t)(i0 + il) * NS + j0 + jl];
        f32x4 rv = *(const f32x4*)&rsb[j0 + jl];
        us4 ev;
#pragma unroll
        for (int r = 0; r < 4; ++r)
          ev[r] = f2bf(__expf(lacc[fr][fc][r] + bf2f(pv[r])) * rv[r]);
        *(us4*)((char*)El + il * 256 + ((jl * 2) ^ ((il & 7) << 4))) = ev;
      }
    __syncthreads();                            // El visible; Aph reads done
    if (jt < 31) stageT(Aph[0], tpb + (size_t)(j0 + 128) * 512, 512, wid, lane);  // overlap with PV
    // ---- PV: yacc[c][i] += g x E over k=j (128) ----
#pragma unroll
    for (int jk = 0; jk < 4; ++jk){
      bf8 eb[4];
#pragma unroll
      for (int f = 0; f < 4; ++f){
        int ei = f * 16 + (lane & 15);
        int ebt = jk * 64 + ((lane >> 4) << 4);
        eb[f] = *(const bf8*)((char*)El + ei * 256 + (ebt ^ ((ei & 7) << 4)));
      }
      __builtin_amdgcn_s_setprio(1);
#pragma unroll
      for (int cf = 0; cf < 4; ++cf){
        int c = wid * 64 + cf * 16 + (lane & 15);
        bf8 ga = *(const bf8*)&gbb[(size_t)c * NS + j0 + jk * 32 + (lane >> 4) * 8];
#pragma unroll
        for (int f = 0; f < 4; ++f)
          yacc[cf][f] = __builtin_amdgcn_mfma_f32_16x16x32_bf16(ga, eb[f], yacc[cf][f], 0, 0, 0);
      }
      __builtin_amdgcn_s_setprio(0);
    }
    __syncthreads();                            // El reads done; next-jt Aph[0] staged
  }
  unsigned short* yo = yb + (size_t)b * NS * NIC;
#pragma unroll
  for (int cf = 0; cf < 4; ++cf)
#pragma unroll
    for (int f = 0; f < 4; ++f){
      int c0 = wid * 64 + cf * 16 + ((lane >> 4) << 2);
      int ig = i0 + f * 16 + (lane & 15);
      us4 v;
#pragma unroll
      for (int r = 0; r < 4; ++r) v[r] = f2bf(yacc[cf][f][r]);
      *(us4*)&yo[(size_t)ig * NIC + c0] = v;
    }
}

// ---------------- mask GEMM + residual ----------------
// out[b][co][n] = sum_ic yb[b][n][ic]*wmb[co][ic] + x   (A = y rows n, B = wm rows co)
__global__ __launch_bounds__(256, 2) void k_out(const unsigned short* yb, const unsigned short* wmb,
                                                const float* xg, float* outg){
  int b = blockIdx.z, cot = blockIdx.y, nt = blockIdx.x;
  int tid = threadIdx.x, wid = tid >> 6, lane = tid & 63, wr = wid >> 1, wc = wid & 1;
  __shared__ unsigned short As[2][8192], Bs[2][8192];
  f32x4 acc[4][4]; zero44(acc);
  gemm128v<4>(yb + ((size_t)b * NS + nt * 128) * 256, 256,
              wmb + (size_t)(cot * 128) * 256, 256, As, Bs, acc, wid, lane);
#pragma unroll
  for (int fr = 0; fr < 4; ++fr)
#pragma unroll
    for (int fc = 0; fc < 4; ++fc){
      int n0 = nt * 128 + wr * 64 + fr * 16 + ((lane >> 4) << 2);
      int co = cot * 128 + wc * 64 + fc * 16 + (lane & 15);
      f32x4 xv = *(const f32x4*)&xg[((size_t)b * NC + co) * NS + n0];
      f32x4 ov = acc[fr][fc] + xv;
      *(f32x4*)&outg[((size_t)b * NC + co) * NS + n0] = ov;
    }
}

extern "C" void kernel_launch(void* const* d_in, const int* in_sizes, int n_in,
                              void* d_out, int out_size, void* d_ws, size_t ws_size,
                              hipStream_t stream){
  const float* x      = (const float*)d_in[0];
  const float* wphi   = (const float*)d_in[1];
  const float* wtheta = (const float*)d_in[2];
  const float* wgf    = (const float*)d_in[3];
  const float* wmf    = (const float*)d_in[4];
  const float* pos    = (const float*)d_in[5];
  const float* pdec   = (const float*)d_in[6];
  float* outg = (float*)d_out;
  char* ws = (char*)d_ws;
  unsigned short* xT   = (unsigned short*)(ws + OFF_XT);
  unsigned short* tp   = (unsigned short*)(ws + OFF_TP);
  unsigned short* posb = (unsigned short*)(ws + OFF_POS);
  unsigned short* gb   = (unsigned short*)(ws + OFF_G);
  float*          rsv  = (float*)(ws + OFF_RS);
  unsigned short* yb   = (unsigned short*)(ws + OFF_Y);
  unsigned short* wtp  = (unsigned short*)(ws + OFF_WTP);
  unsigned short* wgb  = (unsigned short*)(ws + OFF_WG);
  unsigned short* wmb  = (unsigned short*)(ws + OFF_WM);
  float* sp = (float*)(ws + OFF_SP);

  k_prep<<<512, 256, 0, stream>>>(wphi, wtheta, wgf, wmf, wtp, wgb, wmb);
  k_pos<<<8192, 256, 0, stream>>>(pos, posb);
  k_xt<<<dim3(64, 8, 8), 256, 0, stream>>>(x, xT);
  k_tp<<<dim3(32, 4, 8), 256, 0, stream>>>(wtp, xT, tp);
  k_g<<<dim3(32, 2, 8), 256, 0, stream>>>(xT, wgb, pdec, gb);
  k_stats<<<dim3(32, 4, 8), 256, 0, stream>>>(tp, posb, sp);
  k_rs<<<128, 256, 0, stream>>>(sp, rsv);
  k_y<<<dim3(64, 8), 256, 0, stream>>>(tp, posb, gb, rsv, yb);
  k_out<<<dim3(32, 4, 8), 256, 0, stream>>>(yb, wmb, x, outg);
}

// Round 5
// 487.197 us; speedup vs baseline: 1.3677x; 1.0574x over previous
//
#include <hip/hip_runtime.h>

typedef short bf8 __attribute__((ext_vector_type(8)));      // 8 bf16 bit-patterns (4 VGPR) - MFMA A/B frag
typedef float f32x4 __attribute__((ext_vector_type(4)));    // MFMA C/D frag
typedef unsigned short us4 __attribute__((ext_vector_type(4)));
typedef unsigned short us8 __attribute__((ext_vector_type(8)));

#define DEVI __device__ __forceinline__

constexpr int NB = 8, NC = 512, NIC = 256, NS = 4096;   // batch, C, IC, N=H*W

// workspace layout (bytes)
constexpr size_t OFF_XT  = 0;          // xT   [8][4096][512] bf16 (dead after k_g; rs reuses)
constexpr size_t OFF_RS  = 0;          // rs   [8][4096] f32 (1/s_j) - overlays dead xT
constexpr size_t OFF_TP  = 33554432;   // tp   [8][4096][512] bf16 (cols 0-255 phiT, 256-511 thetaT)
constexpr size_t OFF_POS = 67108864;   // posb [4096][4096] bf16
constexpr size_t OFF_G   = 100663296;  // gb   [8][256][4096] bf16  (g + pos_dec, unscaled)
constexpr size_t OFF_G2  = 117440512;  // g2   [8][256][4096] bf16  (gb * rs_j)
constexpr size_t OFF_Y   = 134217728;  // yb   [8][4096][256] bf16
constexpr size_t OFF_WTP = 150994944;  // wtp  [512][512] bf16 (rows 0-255 w_phi, 256-511 w_theta)
constexpr size_t OFF_WG  = 151519232;  // wgb  [256][512] bf16
constexpr size_t OFF_WM  = 151781376;  // wmb  [512][256] bf16
constexpr size_t OFF_SP  = 152043520;  // sp   [8][4][4096] f32 partial column sum-exp

DEVI unsigned short f2bf(float f){
  unsigned u = __float_as_uint(f);
  u += 0x7fffu + ((u >> 16) & 1u);   // RNE
  return (unsigned short)(u >> 16);
}
DEVI float bf2f(unsigned short b){ return __uint_as_float(((unsigned)b) << 16); }

DEVI void gld16(const void* g, void* l){
  __builtin_amdgcn_global_load_lds((const __attribute__((address_space(1))) unsigned int*)g,
                                   (__attribute__((address_space(3))) unsigned int*)l, 16, 0, 0);
}

// stage a [128 rows x 64 cols] bf16 tile (16 KB), XOR-swizzled via pre-swizzled global source.
// physical(row, 16B-chunk c) holds logical chunk c ^ (row&7); LDS dest stays linear (rule #21).
DEVI void stageT(unsigned short* dst, const unsigned short* src, int ld, int wid, int lane){
  int rl = lane >> 3;                                   // row within 8-row group
  int ce = ((lane & 7) << 3) ^ (rl << 3);               // swizzled source col (elems)
#pragma unroll
  for (int it = 0; it < 4; ++it){
    int q = wid + it * 4;                               // wave-uniform instr id 0..15
    gld16(src + (size_t)(q * 8 + rl) * ld + ce, dst + q * 512);
  }
}

DEVI void zero44(f32x4 (&a)[4][4]){
  f32x4 z = {0.f, 0.f, 0.f, 0.f};
#pragma unroll
  for (int i = 0; i < 4; ++i)
#pragma unroll
    for (int j = 0; j < 4; ++j) a[i][j] = z;
}

// 128x128 tile GEMM, K = NK64*64, BK=64, swizzled LDS (conflict-free ds_read_b128),
// 1 barrier per BK=64. A rows = m (stride lda), B rows = n (stride ldb).
// D frag (fr,fc): m = wr*64+fr*16+(lane>>4)*4+reg, n = wc*64+fc*16+(lane&15)
template<int NK64>
DEVI void gemm128v(const unsigned short* Ag, int lda, const unsigned short* Bg, int ldb,
                   unsigned short (&As)[2][8192], unsigned short (&Bs)[2][8192],
                   f32x4 (&acc)[4][4], int wid, int lane)
{
  const int wr = wid >> 1, wc = wid & 1;
  stageT(As[0], Ag, lda, wid, lane);
  stageT(Bs[0], Bg, ldb, wid, lane);
  __syncthreads();
  for (int kt = 0; kt < NK64; ++kt){
    int cur = kt & 1;
    if (kt + 1 < NK64){
      stageT(As[cur ^ 1], Ag + (kt + 1) * 64, lda, wid, lane);
      stageT(Bs[cur ^ 1], Bg + (kt + 1) * 64, ldb, wid, lane);
    }
    bf8 a[2][4], b[2][4];
#pragma unroll
    for (int ks = 0; ks < 2; ++ks){
      int cb = ks * 64 + ((lane >> 4) << 4);
#pragma unroll
      for (int f = 0; f < 4; ++f){
        int rA = wr * 64 + f * 16 + (lane & 15);
        a[ks][f] = *(const bf8*)((char*)As[cur] + rA * 128 + (cb ^ ((rA & 7) << 4)));
        int rB = wc * 64 + f * 16 + (lane & 15);
        b[ks][f] = *(const bf8*)((char*)Bs[cur] + rB * 128 + (cb ^ ((rB & 7) << 4)));
      }
    }
    __builtin_amdgcn_s_setprio(1);
#pragma unroll
    for (int ks = 0; ks < 2; ++ks)
#pragma unroll
      for (int i = 0; i < 4; ++i)
#pragma unroll
        for (int j = 0; j < 4; ++j)
          acc[i][j] = __builtin_amdgcn_mfma_f32_16x16x32_bf16(a[ks][i], b[ks][j], acc[i][j], 0, 0, 0);
    __builtin_amdgcn_s_setprio(0);
    __syncthreads();
  }
}

// ---------------- small prep kernels ----------------

__global__ void k_prep(const float* wphi, const float* wtheta, const float* wgf, const float* wmf,
                       unsigned short* wtp, unsigned short* wgb, unsigned short* wmb){
  int idx = (blockIdx.x * 256 + threadIdx.x) * 4;
  const float* src; unsigned short* dst;
  if (idx < 131072)      { src = wphi + idx;            dst = wtp + idx; }
  else if (idx < 262144) { src = wtheta + (idx - 131072); dst = wtp + idx; }
  else if (idx < 393216) { src = wgf + (idx - 262144);  dst = wgb + (idx - 262144); }
  else                   { src = wmf + (idx - 393216);  dst = wmb + (idx - 393216); }
  f32x4 v = *(const f32x4*)src;
  us4 o;
#pragma unroll
  for (int r = 0; r < 4; ++r) o[r] = f2bf(v[r]);
  *(us4*)dst = o;
}

__global__ void k_pos(const float* pos, unsigned short* posb){
  size_t base = ((size_t)blockIdx.x * 256 + threadIdx.x) * 8;
  f32x4 v0 = *(const f32x4*)&pos[base];
  f32x4 v1 = *(const f32x4*)&pos[base + 4];
  us8 o;
#pragma unroll
  for (int r = 0; r < 4; ++r){ o[r] = f2bf(v0[r]); o[r + 4] = f2bf(v1[r]); }
  *(us8*)&posb[base] = o;
}

// x [b][512][4096] f32 -> xT [b][4096][512] bf16
__global__ void k_xt(const float* x, unsigned short* xT){
  int b = blockIdx.z, ct = blockIdx.y, nt = blockIdx.x;
  __shared__ float t[64][65];
  int tid = threadIdx.x;
  int c0 = ct * 64, n0 = nt * 64;
  const float* xp = x + (size_t)b * NC * NS;
#pragma unroll
  for (int it = 0; it < 16; ++it){
    int idx = it * 256 + tid; int r = idx >> 6, cc = idx & 63;
    t[r][cc] = xp[(size_t)(c0 + r) * NS + n0 + cc];
  }
  __syncthreads();
  unsigned short* xo = xT + (size_t)b * NS * NC;
#pragma unroll
  for (int it = 0; it < 16; ++it){
    int idx = it * 256 + tid; int r = idx >> 6, cc = idx & 63;
    xo[(size_t)(n0 + r) * NC + c0 + cc] = f2bf(t[cc][r]);
  }
}

// ---------------- projection GEMMs ----------------

// tp[b][n][o] = sum_c wtp[o][c] * xT[b][n][c]   (A = wtp rows o, B = xT rows n)
__global__ __launch_bounds__(256, 2) void k_tp(const unsigned short* wtp, const unsigned short* xT,
                                               unsigned short* tp){
  int b = blockIdx.z, ot = blockIdx.y, nt = blockIdx.x;
  int tid = threadIdx.x, wid = tid >> 6, lane = tid & 63, wr = wid >> 1, wc = wid & 1;
  __shared__ unsigned short As[2][8192], Bs[2][8192];
  f32x4 acc[4][4]; zero44(acc);
  gemm128v<8>(wtp + (size_t)(ot * 128) * 512, 512,
              xT + ((size_t)b * NS + nt * 128) * 512, 512, As, Bs, acc, wid, lane);
  unsigned short* out = tp + (size_t)b * NS * 512;
#pragma unroll
  for (int fr = 0; fr < 4; ++fr)
#pragma unroll
    for (int fc = 0; fc < 4; ++fc){
      int o0 = ot * 128 + wr * 64 + fr * 16 + ((lane >> 4) << 2);
      int n  = nt * 128 + wc * 64 + fc * 16 + (lane & 15);
      us4 v;
#pragma unroll
      for (int r = 0; r < 4; ++r) v[r] = f2bf(acc[fr][fc][r]);
      *(us4*)&out[(size_t)n * 512 + o0] = v;
    }
}

// gb[b][o][n] = sum_c xT[b][n][c]*wgb[o][c] + pdec[o][n]   (A = xT rows n, B = wgb rows o)
__global__ __launch_bounds__(256, 2) void k_g(const unsigned short* xT, const unsigned short* wgb,
                                              const float* pdec, unsigned short* gb){
  int b = blockIdx.z, ot = blockIdx.y, nt = blockIdx.x;
  int tid = threadIdx.x, wid = tid >> 6, lane = tid & 63, wr = wid >> 1, wc = wid & 1;
  __shared__ unsigned short As[2][8192], Bs[2][8192];
  f32x4 acc[4][4]; zero44(acc);
  gemm128v<8>(xT + ((size_t)b * NS + nt * 128) * 512, 512,
              wgb + (size_t)(ot * 128) * 512, 512, As, Bs, acc, wid, lane);
#pragma unroll
  for (int fr = 0; fr < 4; ++fr)
#pragma unroll
    for (int fc = 0; fc < 4; ++fc){
      int n0 = nt * 128 + wr * 64 + fr * 16 + ((lane >> 4) << 2);
      int o  = ot * 128 + wc * 64 + fc * 16 + (lane & 15);
      f32x4 pd = *(const f32x4*)&pdec[(size_t)o * NS + n0];
      us4 v;
#pragma unroll
      for (int r = 0; r < 4; ++r) v[r] = f2bf(acc[fr][fc][r] + pd[r]);
      *(us4*)&gb[((size_t)b * NIC + o) * NS + n0] = v;
    }
}

// ---------------- softmax denominators ----------------
// Lt[j][i] = sum_c phiT[j][c]*thetaT[i][c]; sp[b][ih][j] = sum_{i in chunk} exp(Lt + pos[i][j])
__global__ __launch_bounds__(256, 2) void k_stats(const unsigned short* tp, const unsigned short* posb,
                                                  float* sp){
  int b = blockIdx.z, ih = blockIdx.y, jt = blockIdx.x;
  int tid = threadIdx.x, wid = tid >> 6, lane = tid & 63, wr = wid >> 1, wc = wid & 1;
  __shared__ unsigned short As[2][8192], Bs[2][8192];
  __shared__ float sred[2][2][64];
  float sacc[4][4];   // [fr][r] -> local j
#pragma unroll
  for (int i = 0; i < 4; ++i)
#pragma unroll
    for (int j = 0; j < 4; ++j) sacc[i][j] = 0.f;
  const unsigned short* tpb = tp + (size_t)b * NS * 512;
  const unsigned short* Ag = tpb + (size_t)(jt * 128) * 512;         // phiT rows j
  for (int it8 = 0; it8 < 8; ++it8){
    int i0 = (ih * 8 + it8) * 128;
    const unsigned short* Bg = tpb + (size_t)i0 * 512 + 256;         // thetaT rows i
    f32x4 acc[4][4]; zero44(acc);
    gemm128v<4>(Ag, 512, Bg, 512, As, Bs, acc, wid, lane);
#pragma unroll
    for (int fr = 0; fr < 4; ++fr)
#pragma unroll
      for (int fc = 0; fc < 4; ++fc){
        int ig  = i0 + wc * 64 + fc * 16 + (lane & 15);
        int jg0 = jt * 128 + wr * 64 + fr * 16 + ((lane >> 4) << 2);
        us4 pv = *(const us4*)&posb[(size_t)ig * NS + jg0];
#pragma unroll
        for (int r = 0; r < 4; ++r)
          sacc[fr][r] += __expf(acc[fr][fc][r] + bf2f(pv[r]));
      }
  }
#pragma unroll
  for (int m = 1; m <= 8; m <<= 1)
#pragma unroll
    for (int fr = 0; fr < 4; ++fr)
#pragma unroll
      for (int r = 0; r < 4; ++r)
        sacc[fr][r] += __shfl_xor(sacc[fr][r], m, 64);
  if ((lane & 15) == 0){
#pragma unroll
    for (int fr = 0; fr < 4; ++fr)
#pragma unroll
      for (int r = 0; r < 4; ++r)
        sred[wr][wc][fr * 16 + ((lane >> 4) << 2) + r] = sacc[fr][r];
  }
  __syncthreads();
  if (tid < 128){
    int jl = tid;
    sp[((size_t)b * 4 + ih) * NS + jt * 128 + jl] = sred[jl >> 6][0][jl & 63] + sred[jl >> 6][1][jl & 63];
  }
}

// rs[b][j] = 1 / sum_ih sp[b][ih][j]
__global__ void k_rs(const float* sp, float* rs){
  int idx = blockIdx.x * 256 + threadIdx.x;    // 32768 total
  int b = idx >> 12, j = idx & 4095;
  const float* spb = sp + (size_t)b * 4 * NS + j;
  rs[idx] = 1.f / (spb[0] + spb[NS] + spb[2 * NS] + spb[3 * NS]);
}

// g2[b][o][n] = gb[b][o][n] * rs[b][n]
__global__ void k_sg(const unsigned short* gb, const float* rs, unsigned short* g2){
  size_t base = ((size_t)blockIdx.x * 256 + threadIdx.x) * 8;
  int b = (int)(base / ((size_t)NIC * NS));
  int j0 = (int)(base % NS);
  const float* rsb = rs + (size_t)b * NS + j0;
  f32x4 r0 = *(const f32x4*)&rsb[0];
  f32x4 r1 = *(const f32x4*)&rsb[4];
  us8 gv = *(const us8*)&gb[base];
  us8 o;
#pragma unroll
  for (int r = 0; r < 4; ++r){
    o[r]     = f2bf(bf2f(gv[r])     * r0[r]);
    o[r + 4] = f2bf(bf2f(gv[r + 4]) * r1[r]);
  }
  *(us8*)&g2[base] = o;
}

// ---------------- fused  E = exp(L+pos)  and  y = g2 @ E^T ----------------
// 256 threads / 4 waves, i-block 64, j-tile 128, BK=64.
// T3/T4: 4-deep Aph ring, stage 2 chunks ahead, counted vmcnt(32) + raw s_barrier.
// L roles: wave (p=wid>>1 i-half 32, q=wid&1 j-half 64): lacc[4 fr(j)][2 fc(i)], theta in regs (btr).
// PV roles: wave owns 64 c (wid*64), all 64 i -> yacc[4 cf][4 if], E via LDS El.
__global__ __launch_bounds__(256, 2) void k_y(const unsigned short* __restrict__ tp,
                                              const unsigned short* __restrict__ posb,
                                              const unsigned short* __restrict__ g2,
                                              unsigned short* __restrict__ yb){
  int b = blockIdx.y, i0 = blockIdx.x * 64;
  int tid = threadIdx.x, wid = tid >> 6, lane = tid & 63;
  int p = wid >> 1, q = wid & 1;
  __shared__ unsigned short Aph[4][128 * 64];  // phi K-chunk ring, swizzled, 64 KB
  __shared__ unsigned short El[64 * 128];      // E [64 i][128 j], XOR-swizzled, 16 KB
  const unsigned short* tpb = tp + (size_t)b * NS * 512;

  // persistent theta B-frags: btr[kb 0..7][fc 0..1]  (i = i0 + p*32 + fc*16 + lane&15)
  bf8 btr[8][2];
#pragma unroll
  for (int kb = 0; kb < 8; ++kb)
#pragma unroll
    for (int fc = 0; fc < 2; ++fc)
      btr[kb][fc] = *(const bf8*)&tpb[(size_t)(i0 + p * 32 + fc * 16 + (lane & 15)) * 512
                                      + 256 + kb * 32 + (lane >> 4) * 8];

  f32x4 yacc[4][4]; zero44(yacc);              // [cf][if]
  stageT(Aph[0], tpb, 512, wid, lane);         // jt0 ch0
  stageT(Aph[1], tpb + 64, 512, wid, lane);    // jt0 ch1

  const unsigned short* g2b = g2 + (size_t)b * NIC * NS;

  for (int jt = 0; jt < 32; ++jt){
    int j0 = jt * 128;
    const unsigned short* phiBase = tpb + (size_t)j0 * 512;
    const unsigned short* phiNext = tpb + (size_t)(jt < 31 ? j0 + 128 : j0) * 512;
    // prefetch pos for the E-phase (consumed ~4 phases later)
    us4 pv[4][2];
#pragma unroll
    for (int fr = 0; fr < 4; ++fr){
      int jl = q * 64 + fr * 16 + ((lane >> 4) << 2);
#pragma unroll
      for (int fc = 0; fc < 2; ++fc){
        int il = p * 32 + fc * 16 + (lane & 15);
        pv[fr][fc] = *(const us4*)&posb[(size_t)(i0 + il) * NS + j0 + jl];
      }
    }
    f32x4 lacc[4][2];
    {
      f32x4 z = {0.f, 0.f, 0.f, 0.f};
#pragma unroll
      for (int i = 0; i < 4; ++i)
#pragma unroll
        for (int j = 0; j < 2; ++j) lacc[i][j] = z;
    }
    // ---- L phases: 4 x (BK=64, 16 MFMA), counted-vmcnt barriers ----
#pragma unroll
    for (int ph = 0; ph < 4; ++ph){
      // stage chunk ph+2 into ring slot (ph+2)&3 (read 2 barriers later)
      const unsigned short* ssrc = (ph < 2) ? phiBase + (ph + 2) * 64 : phiNext + (ph - 2) * 64;
      stageT(Aph[(ph + 2) & 3], ssrc, 512, wid, lane);
      // wait for chunk ph (all but the 2 newest stages = 32 vmem ops retired)
      asm volatile("s_waitcnt vmcnt(32)" ::: "memory");
      __builtin_amdgcn_s_barrier();
      __builtin_amdgcn_sched_barrier(0);
#pragma unroll
      for (int ks = 0; ks < 2; ++ks){
        bf8 a[4];
#pragma unroll
        for (int fr = 0; fr < 4; ++fr){
          int r = q * 64 + fr * 16 + (lane & 15);
          int cbyte = (ks * 64 + ((lane >> 4) << 4)) ^ ((r & 7) << 4);
          a[fr] = *(const bf8*)((char*)Aph[ph] + r * 128 + cbyte);
        }
        __builtin_amdgcn_s_setprio(1);
#pragma unroll
        for (int fr = 0; fr < 4; ++fr)
#pragma unroll
          for (int fc = 0; fc < 2; ++fc)
            lacc[fr][fc] = __builtin_amdgcn_mfma_f32_16x16x32_bf16(a[fr], btr[ph * 2 + ks][fc],
                                                                   lacc[fr][fc], 0, 0, 0);
        __builtin_amdgcn_s_setprio(0);
      }
    }
    // ---- E-write: E[i][j] = exp(L+pos) -> swizzled El (rs pre-folded into g2) ----
#pragma unroll
    for (int fr = 0; fr < 4; ++fr)
#pragma unroll
      for (int fc = 0; fc < 2; ++fc){
        int il = p * 32 + fc * 16 + (lane & 15);
        int jl = q * 64 + fr * 16 + ((lane >> 4) << 2);
        us4 ev;
#pragma unroll
        for (int r = 0; r < 4; ++r)
          ev[r] = f2bf(__expf(lacc[fr][fc][r] + bf2f(pv[fr][fc][r])));
        *(us4*)((char*)El + il * 256 + ((jl * 2) ^ ((il & 7) << 4))) = ev;
      }
    __builtin_amdgcn_sched_barrier(0);
    asm volatile("s_waitcnt lgkmcnt(0)" ::: "memory");   // El writes visible; do NOT drain vmcnt
    __builtin_amdgcn_s_barrier();
    __builtin_amdgcn_sched_barrier(0);
    // ---- PV: yacc[c][i] += g2 x E over k=j (128) ----
#pragma unroll
    for (int jk = 0; jk < 4; ++jk){
      bf8 eb[4];
#pragma unroll
      for (int f = 0; f < 4; ++f){
        int ei = f * 16 + (lane & 15);
        int ebt = jk * 64 + ((lane >> 4) << 4);
        eb[f] = *(const bf8*)((char*)El + ei * 256 + (ebt ^ ((ei & 7) << 4)));
      }
      __builtin_amdgcn_s_setprio(1);
#pragma unroll
      for (int cf = 0; cf < 4; ++cf){
        int c = wid * 64 + cf * 16 + (lane & 15);
        bf8 ga = *(const bf8*)&g2b[(size_t)c * NS + j0 + jk * 32 + (lane >> 4) * 8];
#pragma unroll
        for (int f = 0; f < 4; ++f)
          yacc[cf][f] = __builtin_amdgcn_mfma_f32_16x16x32_bf16(ga, eb[f], yacc[cf][f], 0, 0, 0);
      }
      __builtin_amdgcn_s_setprio(0);
    }
    // no post-PV barrier: El reads retire before each wave's next phase barrier,
    // and the next El write is 4 barriers away.
  }
  unsigned short* yo = yb + (size_t)b * NS * NIC;
#pragma unroll
  for (int cf = 0; cf < 4; ++cf)
#pragma unroll
    for (int f = 0; f < 4; ++f){
      int c0 = wid * 64 + cf * 16 + ((lane >> 4) << 2);
      int ig = i0 + f * 16 + (lane & 15);
      us4 v;
#pragma unroll
      for (int r = 0; r < 4; ++r) v[r] = f2bf(yacc[cf][f][r]);
      *(us4*)&yo[(size_t)ig * NIC + c0] = v;
    }
}

// ---------------- mask GEMM + residual ----------------
// out[b][co][n] = sum_ic yb[b][n][ic]*wmb[co][ic] + x   (A = y rows n, B = wm rows co)
__global__ __launch_bounds__(256, 2) void k_out(const unsigned short* yb, const unsigned short* wmb,
                                                const float* xg, float* outg){
  int b = blockIdx.z, cot = blockIdx.y, nt = blockIdx.x;
  int tid = threadIdx.x, wid = tid >> 6, lane = tid & 63, wr = wid >> 1, wc = wid & 1;
  __shared__ unsigned short As[2][8192], Bs[2][8192];
  f32x4 acc[4][4]; zero44(acc);
  gemm128v<4>(yb + ((size_t)b * NS + nt * 128) * 256, 256,
              wmb + (size_t)(cot * 128) * 256, 256, As, Bs, acc, wid, lane);
#pragma unroll
  for (int fr = 0; fr < 4; ++fr)
#pragma unroll
    for (int fc = 0; fc < 4; ++fc){
      int n0 = nt * 128 + wr * 64 + fr * 16 + ((lane >> 4) << 2);
      int co = cot * 128 + wc * 64 + fc * 16 + (lane & 15);
      f32x4 xv = *(const f32x4*)&xg[((size_t)b * NC + co) * NS + n0];
      f32x4 ov = acc[fr][fc] + xv;
      *(f32x4*)&outg[((size_t)b * NC + co) * NS + n0] = ov;
    }
}

extern "C" void kernel_launch(void* const* d_in, const int* in_sizes, int n_in,
                              void* d_out, int out_size, void* d_ws, size_t ws_size,
                              hipStream_t stream){
  const float* x      = (const float*)d_in[0];
  const float* wphi   = (const float*)d_in[1];
  const float* wtheta = (const float*)d_in[2];
  const float* wgf    = (const float*)d_in[3];
  const float* wmf    = (const float*)d_in[4];
  const float* pos    = (const float*)d_in[5];
  const float* pdec   = (const float*)d_in[6];
  float* outg = (float*)d_out;
  char* ws = (char*)d_ws;
  unsigned short* xT   = (unsigned short*)(ws + OFF_XT);
  float*          rsv  = (float*)(ws + OFF_RS);          // overlays xT (dead after k_g)
  unsigned short* tp   = (unsigned short*)(ws + OFF_TP);
  unsigned short* posb = (unsigned short*)(ws + OFF_POS);
  unsigned short* gb   = (unsigned short*)(ws + OFF_G);
  unsigned short* g2   = (unsigned short*)(ws + OFF_G2);
  unsigned short* yb   = (unsigned short*)(ws + OFF_Y);
  unsigned short* wtp  = (unsigned short*)(ws + OFF_WTP);
  unsigned short* wgb  = (unsigned short*)(ws + OFF_WG);
  unsigned short* wmb  = (unsigned short*)(ws + OFF_WM);
  float* sp = (float*)(ws + OFF_SP);

  k_prep<<<512, 256, 0, stream>>>(wphi, wtheta, wgf, wmf, wtp, wgb, wmb);
  k_pos<<<8192, 256, 0, stream>>>(pos, posb);
  k_xt<<<dim3(64, 8, 8), 256, 0, stream>>>(x, xT);
  k_tp<<<dim3(32, 4, 8), 256, 0, stream>>>(wtp, xT, tp);
  k_g<<<dim3(32, 2, 8), 256, 0, stream>>>(xT, wgb, pdec, gb);
  k_stats<<<dim3(32, 4, 8), 256, 0, stream>>>(tp, posb, sp);
  k_rs<<<128, 256, 0, stream>>>(sp, rsv);
  k_sg<<<4096, 256, 0, stream>>>(gb, rsv, g2);
  k_y<<<dim3(64, 8), 256, 0, stream>>>(tp, posb, g2, yb);
  k_out<<<dim3(32, 4, 8), 256, 0, stream>>>(yb, wmb, x, outg);
}

// Round 7
// 483.540 us; speedup vs baseline: 1.3780x; 1.0076x over previous
//
#include <hip/hip_runtime.h>

typedef short bf8 __attribute__((ext_vector_type(8)));      // 8 bf16 bit-patterns (4 VGPR) - MFMA A/B frag
typedef float f32x4 __attribute__((ext_vector_type(4)));    // MFMA C/D frag
typedef unsigned short us4 __attribute__((ext_vector_type(4)));
typedef unsigned short us8 __attribute__((ext_vector_type(8)));

#define DEVI __device__ __forceinline__

constexpr int NB = 8, NC = 512, NIC = 256, NS = 4096;   // batch, C, IC, N=H*W

// workspace layout (bytes)
constexpr size_t OFF_XT  = 0;          // xT   [8][4096][512] bf16 (dead after k_g; rs reuses)
constexpr size_t OFF_RS  = 0;          // rs   [8][4096] f32 (1/s_j) - overlays dead xT
constexpr size_t OFF_TP  = 33554432;   // tp   [8][4096][512] bf16 (cols 0-255 phiT, 256-511 thetaT)
constexpr size_t OFF_POS = 67108864;   // posb [4096][4096] bf16
constexpr size_t OFF_G   = 100663296;  // gb   [8][256][4096] bf16  (g + pos_dec, unscaled)
constexpr size_t OFF_G2  = 117440512;  // g2   [8][256][4096] bf16  (gb * rs_j)
constexpr size_t OFF_Y   = 134217728;  // yb   [8][4096][256] bf16
constexpr size_t OFF_WTP = 150994944;  // wtp  [512][512] bf16 (rows 0-255 w_phi, 256-511 w_theta)
constexpr size_t OFF_WG  = 151519232;  // wgb  [256][512] bf16
constexpr size_t OFF_WM  = 151781376;  // wmb  [512][256] bf16

DEVI unsigned short f2bf(float f){
  unsigned u = __float_as_uint(f);
  u += 0x7fffu + ((u >> 16) & 1u);   // RNE
  return (unsigned short)(u >> 16);
}
DEVI float bf2f(unsigned short b){ return __uint_as_float(((unsigned)b) << 16); }

DEVI void gld16(const void* g, void* l){
  __builtin_amdgcn_global_load_lds((const __attribute__((address_space(1))) unsigned int*)g,
                                   (__attribute__((address_space(3))) unsigned int*)l, 16, 0, 0);
}

// stage a [128 rows x 64 cols] bf16 tile (16 KB), XOR-swizzled via pre-swizzled global source.
// physical(row, 16B-chunk c) holds logical chunk c ^ (row&7); LDS dest stays linear (rule #21).
// 4 global_load_lds instructions per lane.
DEVI void stageT(unsigned short* dst, const unsigned short* src, int ld, int wid, int lane){
  int rl = lane >> 3;                                   // row within 8-row group
  int ce = ((lane & 7) << 3) ^ (rl << 3);               // swizzled source col (elems)
#pragma unroll
  for (int it = 0; it < 4; ++it){
    int q = wid + it * 4;                               // wave-uniform instr id 0..15
    gld16(src + (size_t)(q * 8 + rl) * ld + ce, dst + q * 512);
  }
}

DEVI void zero44(f32x4 (&a)[4][4]){
  f32x4 z = {0.f, 0.f, 0.f, 0.f};
#pragma unroll
  for (int i = 0; i < 4; ++i)
#pragma unroll
    for (int j = 0; j < 4; ++j) a[i][j] = z;
}

// 128x128 tile GEMM, K = NK64*64, BK=64, swizzled LDS (conflict-free ds_read_b128),
// 1 barrier per BK=64. A rows = m (stride lda), B rows = n (stride ldb).
// D frag (fr,fc): m = wr*64+fr*16+(lane>>4)*4+reg, n = wc*64+fc*16+(lane&15)
template<int NK64>
DEVI void gemm128v(const unsigned short* Ag, int lda, const unsigned short* Bg, int ldb,
                   unsigned short (&As)[2][8192], unsigned short (&Bs)[2][8192],
                   f32x4 (&acc)[4][4], int wid, int lane)
{
  const int wr = wid >> 1, wc = wid & 1;
  stageT(As[0], Ag, lda, wid, lane);
  stageT(Bs[0], Bg, ldb, wid, lane);
  __syncthreads();
  for (int kt = 0; kt < NK64; ++kt){
    int cur = kt & 1;
    if (kt + 1 < NK64){
      stageT(As[cur ^ 1], Ag + (kt + 1) * 64, lda, wid, lane);
      stageT(Bs[cur ^ 1], Bg + (kt + 1) * 64, ldb, wid, lane);
    }
    bf8 a[2][4], b[2][4];
#pragma unroll
    for (int ks = 0; ks < 2; ++ks){
      int cb = ks * 64 + ((lane >> 4) << 4);
#pragma unroll
      for (int f = 0; f < 4; ++f){
        int rA = wr * 64 + f * 16 + (lane & 15);
        a[ks][f] = *(const bf8*)((char*)As[cur] + rA * 128 + (cb ^ ((rA & 7) << 4)));
        int rB = wc * 64 + f * 16 + (lane & 15);
        b[ks][f] = *(const bf8*)((char*)Bs[cur] + rB * 128 + (cb ^ ((rB & 7) << 4)));
      }
    }
    __builtin_amdgcn_s_setprio(1);
#pragma unroll
    for (int ks = 0; ks < 2; ++ks)
#pragma unroll
      for (int i = 0; i < 4; ++i)
#pragma unroll
        for (int j = 0; j < 4; ++j)
          acc[i][j] = __builtin_amdgcn_mfma_f32_16x16x32_bf16(a[ks][i], b[ks][j], acc[i][j], 0, 0, 0);
    __builtin_amdgcn_s_setprio(0);
    __syncthreads();
  }
}

// ---------------- small prep kernels ----------------

__global__ void k_prep(const float* wphi, const float* wtheta, const float* wgf, const float* wmf,
                       unsigned short* wtp, unsigned short* wgb, unsigned short* wmb){
  int idx = (blockIdx.x * 256 + threadIdx.x) * 4;
  const float* src; unsigned short* dst;
  if (idx < 131072)      { src = wphi + idx;            dst = wtp + idx; }
  else if (idx < 262144) { src = wtheta + (idx - 131072); dst = wtp + idx; }
  else if (idx < 393216) { src = wgf + (idx - 262144);  dst = wgb + (idx - 262144); }
  else                   { src = wmf + (idx - 393216);  dst = wmb + (idx - 393216); }
  f32x4 v = *(const f32x4*)src;
  us4 o;
#pragma unroll
  for (int r = 0; r < 4; ++r) o[r] = f2bf(v[r]);
  *(us4*)dst = o;
}

__global__ void k_pos(const float* pos, unsigned short* posb){
  size_t base = ((size_t)blockIdx.x * 256 + threadIdx.x) * 8;
  f32x4 v0 = *(const f32x4*)&pos[base];
  f32x4 v1 = *(const f32x4*)&pos[base + 4];
  us8 o;
#pragma unroll
  for (int r = 0; r < 4; ++r){ o[r] = f2bf(v0[r]); o[r + 4] = f2bf(v1[r]); }
  *(us8*)&posb[base] = o;
}

// x [b][512][4096] f32 -> xT [b][4096][512] bf16
__global__ void k_xt(const float* x, unsigned short* xT){
  int b = blockIdx.z, ct = blockIdx.y, nt = blockIdx.x;
  __shared__ float t[64][65];
  int tid = threadIdx.x;
  int c0 = ct * 64, n0 = nt * 64;
  const float* xp = x + (size_t)b * NC * NS;
#pragma unroll
  for (int it = 0; it < 16; ++it){
    int idx = it * 256 + tid; int r = idx >> 6, cc = idx & 63;
    t[r][cc] = xp[(size_t)(c0 + r) * NS + n0 + cc];
  }
  __syncthreads();
  unsigned short* xo = xT + (size_t)b * NS * NC;
#pragma unroll
  for (int it = 0; it < 16; ++it){
    int idx = it * 256 + tid; int r = idx >> 6, cc = idx & 63;
    xo[(size_t)(n0 + r) * NC + c0 + cc] = f2bf(t[cc][r]);
  }
}

// ---------------- projection GEMMs ----------------

// tp[b][n][o] = sum_c wtp[o][c] * xT[b][n][c]   (A = wtp rows o, B = xT rows n)
__global__ __launch_bounds__(256, 2) void k_tp(const unsigned short* wtp, const unsigned short* xT,
                                               unsigned short* tp){
  int b = blockIdx.z, ot = blockIdx.y, nt = blockIdx.x;
  int tid = threadIdx.x, wid = tid >> 6, lane = tid & 63, wr = wid >> 1, wc = wid & 1;
  __shared__ unsigned short As[2][8192], Bs[2][8192];
  f32x4 acc[4][4]; zero44(acc);
  gemm128v<8>(wtp + (size_t)(ot * 128) * 512, 512,
              xT + ((size_t)b * NS + nt * 128) * 512, 512, As, Bs, acc, wid, lane);
  unsigned short* out = tp + (size_t)b * NS * 512;
#pragma unroll
  for (int fr = 0; fr < 4; ++fr)
#pragma unroll
    for (int fc = 0; fc < 4; ++fc){
      int o0 = ot * 128 + wr * 64 + fr * 16 + ((lane >> 4) << 2);
      int n  = nt * 128 + wc * 64 + fc * 16 + (lane & 15);
      us4 v;
#pragma unroll
      for (int r = 0; r < 4; ++r) v[r] = f2bf(acc[fr][fc][r]);
      *(us4*)&out[(size_t)n * 512 + o0] = v;
    }
}

// gb[b][o][n] = sum_c xT[b][n][c]*wgb[o][c] + pdec[o][n]   (A = xT rows n, B = wgb rows o)
__global__ __launch_bounds__(256, 2) void k_g(const unsigned short* xT, const unsigned short* wgb,
                                              const float* pdec, unsigned short* gb){
  int b = blockIdx.z, ot = blockIdx.y, nt = blockIdx.x;
  int tid = threadIdx.x, wid = tid >> 6, lane = tid & 63, wr = wid >> 1, wc = wid & 1;
  __shared__ unsigned short As[2][8192], Bs[2][8192];
  f32x4 acc[4][4]; zero44(acc);
  gemm128v<8>(xT + ((size_t)b * NS + nt * 128) * 512, 512,
              wgb + (size_t)(ot * 128) * 512, 512, As, Bs, acc, wid, lane);
#pragma unroll
  for (int fr = 0; fr < 4; ++fr)
#pragma unroll
    for (int fc = 0; fc < 4; ++fc){
      int n0 = nt * 128 + wr * 64 + fr * 16 + ((lane >> 4) << 2);
      int o  = ot * 128 + wc * 64 + fc * 16 + (lane & 15);
      f32x4 pd = *(const f32x4*)&pdec[(size_t)o * NS + n0];
      us4 v;
#pragma unroll
      for (int r = 0; r < 4; ++r) v[r] = f2bf(acc[fr][fc][r] + pd[r]);
      *(us4*)&gb[((size_t)b * NIC + o) * NS + n0] = v;
    }
}

// ---------------- softmax denominators (ring structure, swapped operands) ----------------
// Block = 64 j (phi in regs), loops 32 i-tiles of 128 (theta via 4-deep swizzled ring).
// rs[b][j] = 1 / sum_i exp(L[i,j] + pos[i,j]) written directly.
// Waves: p = wid>>1 (j-half 32), q = wid&1 (i-half 64).
// Exact waits: ph0/1 target staged 2 phases back; newer = 1 stage + 8 pos + 1 stage = 16.
//              ph2/3 newer = 2 stages = 8.
__global__ __launch_bounds__(256, 2) void k_stats(const unsigned short* __restrict__ tp,
                                                  const unsigned short* __restrict__ posb,
                                                  float* __restrict__ rs){
  int bid = blockIdx.x;
  int b = bid & 7, jb0 = (bid >> 3) * 64;      // XCD-pinned batches
  int tid = threadIdx.x, wid = tid >> 6, lane = tid & 63;
  int p = wid >> 1, q = wid & 1, h = lane >> 4, l15 = lane & 15;
  __shared__ unsigned short Ath[4][128 * 64];  // theta K-chunk ring, swizzled, 64 KB
  __shared__ float red[64];
  const unsigned short* tpb = tp + (size_t)b * NS * 512;

  // persistent phi A-frags: bphi[kb 0..7][frj 0..1]; j = jb0 + p*32 + frj*16 + l15
  bf8 bphi[8][2];
#pragma unroll
  for (int kb = 0; kb < 8; ++kb)
#pragma unroll
    for (int frj = 0; frj < 2; ++frj)
      bphi[kb][frj] = *(const bf8*)&tpb[(size_t)(jb0 + p * 32 + frj * 16 + l15) * 512
                                        + kb * 32 + h * 8];

  float sacc[2][4];
#pragma unroll
  for (int a = 0; a < 2; ++a)
#pragma unroll
    for (int r = 0; r < 4; ++r) sacc[a][r] = 0.f;

  stageT(Ath[0], tpb + 256, 512, wid, lane);        // tile0 chunk0 (theta = cols 256+)
  stageT(Ath[1], tpb + 256 + 64, 512, wid, lane);   // tile0 chunk1

  for (int it = 0; it < 32; ++it){
    int i0t = it * 128;
    const unsigned short* thBase = tpb + (size_t)i0t * 512 + 256;
    const unsigned short* thNext = tpb + (size_t)(it < 31 ? i0t + 128 : i0t) * 512 + 256;
    // prefetch pos (contiguous in j -> us4 over r): 8 vmem loads
    us4 pv[2][4];
#pragma unroll
    for (int frj = 0; frj < 2; ++frj)
#pragma unroll
      for (int fci = 0; fci < 4; ++fci){
        int iG = i0t + q * 64 + fci * 16 + l15;
        int jG = jb0 + p * 32 + frj * 16 + h * 4;
        pv[frj][fci] = *(const us4*)&posb[(size_t)iG * NS + jG];
      }
    f32x4 lacc[2][4];
    {
      f32x4 z = {0.f, 0.f, 0.f, 0.f};
#pragma unroll
      for (int a = 0; a < 2; ++a)
#pragma unroll
        for (int c = 0; c < 4; ++c) lacc[a][c] = z;
    }
#pragma unroll
    for (int ph = 0; ph < 4; ++ph){
      const unsigned short* ssrc = (ph < 2) ? thBase + (ph + 2) * 64 : thNext + (ph - 2) * 64;
      stageT(Ath[(ph + 2) & 3], ssrc, 512, wid, lane);
      if (ph < 2) asm volatile("s_waitcnt vmcnt(16)" ::: "memory");
      else        asm volatile("s_waitcnt vmcnt(8)"  ::: "memory");
      __builtin_amdgcn_s_barrier();
      __builtin_amdgcn_sched_barrier(0);
#pragma unroll
      for (int ks = 0; ks < 2; ++ks){
        bf8 tfr[4];
#pragma unroll
        for (int fci = 0; fci < 4; ++fci){
          int rI = q * 64 + fci * 16 + l15;
          int cbyte = (ks * 64 + (h << 4)) ^ ((rI & 7) << 4);
          tfr[fci] = *(const bf8*)((char*)Ath[ph] + rI * 128 + cbyte);
        }
        __builtin_amdgcn_s_setprio(1);
#pragma unroll
        for (int frj = 0; frj < 2; ++frj)
#pragma unroll
          for (int fci = 0; fci < 4; ++fci)
            lacc[frj][fci] = __builtin_amdgcn_mfma_f32_16x16x32_bf16(bphi[ph * 2 + ks][frj], tfr[fci],
                                                                     lacc[frj][fci], 0, 0, 0);
        __builtin_amdgcn_s_setprio(0);
      }
    }
    // exp + accumulate over i (fci in-register)
#pragma unroll
    for (int frj = 0; frj < 2; ++frj)
#pragma unroll
      for (int fci = 0; fci < 4; ++fci)
#pragma unroll
        for (int r = 0; r < 4; ++r)
          sacc[frj][r] += __expf(lacc[frj][fci][r] + bf2f(pv[frj][fci][r]));
  }
  // reduce over the 16 lanes of each group (i-direction)
#pragma unroll
  for (int m = 1; m <= 8; m <<= 1)
#pragma unroll
    for (int frj = 0; frj < 2; ++frj)
#pragma unroll
      for (int r = 0; r < 4; ++r)
        sacc[frj][r] += __shfl_xor(sacc[frj][r], m, 64);
  // cross-q reduce + write rs
  if (q == 0 && l15 == 0){
#pragma unroll
    for (int frj = 0; frj < 2; ++frj)
#pragma unroll
      for (int r = 0; r < 4; ++r)
        red[p * 32 + frj * 16 + h * 4 + r] = sacc[frj][r];
  }
  __syncthreads();
  if (q == 1 && l15 == 0){
#pragma unroll
    for (int frj = 0; frj < 2; ++frj)
#pragma unroll
      for (int r = 0; r < 4; ++r){
        int jl = p * 32 + frj * 16 + h * 4 + r;
        float s = sacc[frj][r] + red[jl];
        rs[(size_t)b * NS + jb0 + jl] = 1.f / s;
      }
  }
}

// g2[b][o][n] = gb[b][o][n] * rs[b][n]
__global__ void k_sg(const unsigned short* gb, const float* rs, unsigned short* g2){
  size_t base = ((size_t)blockIdx.x * 256 + threadIdx.x) * 8;
  int b = (int)(base / ((size_t)NIC * NS));
  int j0 = (int)(base % NS);
  const float* rsb = rs + (size_t)b * NS + j0;
  f32x4 r0 = *(const f32x4*)&rsb[0];
  f32x4 r1 = *(const f32x4*)&rsb[4];
  us8 gv = *(const us8*)&gb[base];
  us8 o;
#pragma unroll
  for (int r = 0; r < 4; ++r){
    o[r]     = f2bf(bf2f(gv[r])     * r0[r]);
    o[r + 4] = f2bf(bf2f(gv[r + 4]) * r1[r]);
  }
  *(us8*)&g2[base] = o;
}

// ---------------- fused  E = exp(L+pos)  and  y = g2 @ E^T ----------------
// 256 threads / 4 waves, i-block 64, j-tile 128, BK=64.
// 4-deep Aph ring, stage 2 chunks ahead, exact counted vmcnt + raw s_barrier.
// ph0/1: vmcnt(16) (exact at jt=0; at jt>0 ga loads already retired via PV MFMA waits).
// ph2/3: vmcnt(8) (newer = 2 stages).
__global__ __launch_bounds__(256, 2) void k_y(const unsigned short* __restrict__ tp,
                                              const unsigned short* __restrict__ posb,
                                              const unsigned short* __restrict__ g2,
                                              unsigned short* __restrict__ yb){
  int bid = blockIdx.x;
  int b = bid & 7, i0 = (bid >> 3) * 64;       // XCD-pinned batches
  int tid = threadIdx.x, wid = tid >> 6, lane = tid & 63;
  int p = wid >> 1, q = wid & 1;
  __shared__ unsigned short Aph[4][128 * 64];  // phi K-chunk ring, swizzled, 64 KB
  __shared__ unsigned short El[64 * 128];      // E [64 i][128 j], XOR-swizzled, 16 KB
  const unsigned short* tpb = tp + (size_t)b * NS * 512;

  // persistent theta B-frags: btr[kb 0..7][fc 0..1]  (i = i0 + p*32 + fc*16 + lane&15)
  bf8 btr[8][2];
#pragma unroll
  for (int kb = 0; kb < 8; ++kb)
#pragma unroll
    for (int fc = 0; fc < 2; ++fc)
      btr[kb][fc] = *(const bf8*)&tpb[(size_t)(i0 + p * 32 + fc * 16 + (lane & 15)) * 512
                                      + 256 + kb * 32 + (lane >> 4) * 8];

  f32x4 yacc[4][4]; zero44(yacc);              // [cf][if]
  stageT(Aph[0], tpb, 512, wid, lane);         // jt0 ch0
  stageT(Aph[1], tpb + 64, 512, wid, lane);    // jt0 ch1

  const unsigned short* g2b = g2 + (size_t)b * NIC * NS;

  for (int jt = 0; jt < 32; ++jt){
    int j0 = jt * 128;
    const unsigned short* phiBase = tpb + (size_t)j0 * 512;
    const unsigned short* phiNext = tpb + (size_t)(jt < 31 ? j0 + 128 : j0) * 512;
    // prefetch pos for the E-phase: 8 vmem loads
    us4 pv[4][2];
#pragma unroll
    for (int fr = 0; fr < 4; ++fr){
      int jl = q * 64 + fr * 16 + ((lane >> 4) << 2);
#pragma unroll
      for (int fc = 0; fc < 2; ++fc){
        int il = p * 32 + fc * 16 + (lane & 15);
        pv[fr][fc] = *(const us4*)&posb[(size_t)(i0 + il) * NS + j0 + jl];
      }
    }
    f32x4 lacc[4][2];
    {
      f32x4 z = {0.f, 0.f, 0.f, 0.f};
#pragma unroll
      for (int i = 0; i < 4; ++i)
#pragma unroll
        for (int j = 0; j < 2; ++j) lacc[i][j] = z;
    }
    // ---- L phases: 4 x (BK=64, 16 MFMA), exact counted-vmcnt barriers ----
#pragma unroll
    for (int ph = 0; ph < 4; ++ph){
      // stage chunk ph+2 into ring slot (ph+2)&3 (read 2 barriers later)
      const unsigned short* ssrc = (ph < 2) ? phiBase + (ph + 2) * 64 : phiNext + (ph - 2) * 64;
      stageT(Aph[(ph + 2) & 3], ssrc, 512, wid, lane);
      if (ph < 2) asm volatile("s_waitcnt vmcnt(16)" ::: "memory");
      else        asm volatile("s_waitcnt vmcnt(8)"  ::: "memory");
      __builtin_amdgcn_s_barrier();
      __builtin_amdgcn_sched_barrier(0);
#pragma unroll
      for (int ks = 0; ks < 2; ++ks){
        bf8 a[4];
#pragma unroll
        for (int fr = 0; fr < 4; ++fr){
          int r = q * 64 + fr * 16 + (lane & 15);
          int cbyte = (ks * 64 + ((lane >> 4) << 4)) ^ ((r & 7) << 4);
          a[fr] = *(const bf8*)((char*)Aph[ph] + r * 128 + cbyte);
        }
        __builtin_amdgcn_s_setprio(1);
#pragma unroll
        for (int fr = 0; fr < 4; ++fr)
#pragma unroll
          for (int fc = 0; fc < 2; ++fc)
            lacc[fr][fc] = __builtin_amdgcn_mfma_f32_16x16x32_bf16(a[fr], btr[ph * 2 + ks][fc],
                                                                   lacc[fr][fc], 0, 0, 0);
        __builtin_amdgcn_s_setprio(0);
      }
    }
    // ---- E-write: E[i][j] = exp(L+pos) -> swizzled El (rs pre-folded into g2) ----
#pragma unroll
    for (int fr = 0; fr < 4; ++fr)
#pragma unroll
      for (int fc = 0; fc < 2; ++fc){
        int il = p * 32 + fc * 16 + (lane & 15);
        int jl = q * 64 + fr * 16 + ((lane >> 4) << 2);
        us4 ev;
#pragma unroll
        for (int r = 0; r < 4; ++r)
          ev[r] = f2bf(__expf(lacc[fr][fc][r] + bf2f(pv[fr][fc][r])));
        *(us4*)((char*)El + il * 256 + ((jl * 2) ^ ((il & 7) << 4))) = ev;
      }
    __builtin_amdgcn_sched_barrier(0);
    asm volatile("s_waitcnt lgkmcnt(0)" ::: "memory");   // El writes visible; do NOT drain vmcnt
    __builtin_amdgcn_s_barrier();
    __builtin_amdgcn_sched_barrier(0);
    // ---- PV: yacc[c][i] += g2 x E over k=j (128) ----
#pragma unroll
    for (int jk = 0; jk < 4; ++jk){
      bf8 eb[4];
#pragma unroll
      for (int f = 0; f < 4; ++f){
        int ei = f * 16 + (lane & 15);
        int ebt = jk * 64 + ((lane >> 4) << 4);
        eb[f] = *(const bf8*)((char*)El + ei * 256 + (ebt ^ ((ei & 7) << 4)));
      }
      __builtin_amdgcn_s_setprio(1);
#pragma unroll
      for (int cf = 0; cf < 4; ++cf){
        int c = wid * 64 + cf * 16 + (lane & 15);
        bf8 ga = *(const bf8*)&g2b[(size_t)c * NS + j0 + jk * 32 + (lane >> 4) * 8];
#pragma unroll
        for (int f = 0; f < 4; ++f)
          yacc[cf][f] = __builtin_amdgcn_mfma_f32_16x16x32_bf16(ga, eb[f], yacc[cf][f], 0, 0, 0);
      }
      __builtin_amdgcn_s_setprio(0);
    }
    // no post-PV barrier: El reads are consumed (register deps) before any wave
    // reaches the next El write, which is 4 phase-barriers away.
  }
  unsigned short* yo = yb + (size_t)b * NS * NIC;
#pragma unroll
  for (int cf = 0; cf < 4; ++cf)
#pragma unroll
    for (int f = 0; f < 4; ++f){
      int c0 = wid * 64 + cf * 16 + ((lane >> 4) << 2);
      int ig = i0 + f * 16 + (lane & 15);
      us4 v;
#pragma unroll
      for (int r = 0; r < 4; ++r) v[r] = f2bf(yacc[cf][f][r]);
      *(us4*)&yo[(size_t)ig * NIC + c0] = v;
    }
}

// ---------------- mask GEMM + residual ----------------
// out[b][co][n] = sum_ic yb[b][n][ic]*wmb[co][ic] + x   (A = y rows n, B = wm rows co)
__global__ __launch_bounds__(256, 2) void k_out(const unsigned short* yb, const unsigned short* wmb,
                                                const float* xg, float* outg){
  int b = blockIdx.z, cot = blockIdx.y, nt = blockIdx.x;
  int tid = threadIdx.x, wid = tid >> 6, lane = tid & 63, wr = wid >> 1, wc = wid & 1;
  __shared__ unsigned short As[2][8192], Bs[2][8192];
  f32x4 acc[4][4]; zero44(acc);
  gemm128v<4>(yb + ((size_t)b * NS + nt * 128) * 256, 256,
              wmb + (size_t)(cot * 128) * 256, 256, As, Bs, acc, wid, lane);
#pragma unroll
  for (int fr = 0; fr < 4; ++fr)
#pragma unroll
    for (int fc = 0; fc < 4; ++fc){
      int n0 = nt * 128 + wr * 64 + fr * 16 + ((lane >> 4) << 2);
      int co = cot * 128 + wc * 64 + fc * 16 + (lane & 15);
      f32x4 xv = *(const f32x4*)&xg[((size_t)b * NC + co) * NS + n0];
      f32x4 ov = acc[fr][fc] + xv;
      *(f32x4*)&outg[((size_t)b * NC + co) * NS + n0] = ov;
    }
}

extern "C" void kernel_launch(void* const* d_in, const int* in_sizes, int n_in,
                              void* d_out, int out_size, void* d_ws, size_t ws_size,
                              hipStream_t stream){
  const float* x      = (const float*)d_in[0];
  const float* wphi   = (const float*)d_in[1];
  const float* wtheta = (const float*)d_in[2];
  const float* wgf    = (const float*)d_in[3];
  const float* wmf    = (const float*)d_in[4];
  const float* pos    = (const float*)d_in[5];
  const float* pdec   = (const float*)d_in[6];
  float* outg = (float*)d_out;
  char* ws = (char*)d_ws;
  unsigned short* xT   = (unsigned short*)(ws + OFF_XT);
  float*          rsv  = (float*)(ws + OFF_RS);          // overlays xT (dead after k_g)
  unsigned short* tp   = (unsigned short*)(ws + OFF_TP);
  unsigned short* posb = (unsigned short*)(ws + OFF_POS);
  unsigned short* gb   = (unsigned short*)(ws + OFF_G);
  unsigned short* g2   = (unsigned short*)(ws + OFF_G2);
  unsigned short* yb   = (unsigned short*)(ws + OFF_Y);
  unsigned short* wtp  = (unsigned short*)(ws + OFF_WTP);
  unsigned short* wgb  = (unsigned short*)(ws + OFF_WG);
  unsigned short* wmb  = (unsigned short*)(ws + OFF_WM);

  k_prep<<<512, 256, 0, stream>>>(wphi, wtheta, wgf, wmf, wtp, wgb, wmb);
  k_pos<<<8192, 256, 0, stream>>>(pos, posb);
  k_xt<<<dim3(64, 8, 8), 256, 0, stream>>>(x, xT);
  k_tp<<<dim3(32, 4, 8), 256, 0, stream>>>(wtp, xT, tp);
  k_g<<<dim3(32, 2, 8), 256, 0, stream>>>(xT, wgb, pdec, gb);
  k_stats<<<512, 256, 0, stream>>>(tp, posb, rsv);
  k_sg<<<4096, 256, 0, stream>>>(gb, rsv, g2);
  k_y<<<512, 256, 0, stream>>>(tp, posb, g2, yb);
  k_out<<<dim3(32, 4, 8), 256, 0, stream>>>(yb, wmb, x, outg);
}